// Round 1
// baseline (11775.511 us; speedup 1.0000x reference)
//
#include <hip/hip_runtime.h>
#include <math.h>

#define N16 1600
#define M 32
#define T_OUTER 24
#define P_INNER 8
#define NSWEEP 14
#define EPSF 1e-12f

// ---------------- resize (jax.image.resize bilinear, antialias=True) --------
__device__ inline void taps1d(int o, int* lo, int* hi, float* wsum, float w[8]) {
  int l = 4 * o - 2, h = 4 * o + 5;
  if (l < 0) l = 0;
  if (h > 159) h = 159;
  float c = 4.f * o + 1.5f, s = 0.f;
  for (int x = l; x <= h; ++x) {
    float ww = 1.f - fabsf((float)x - c) * 0.25f;
    w[x - l] = ww;
    s += ww;
  }
  *lo = l; *hi = h; *wsum = s;
}

__global__ void k_resize(const float* __restrict__ in, float* __restrict__ rz) {
  int map = blockIdx.y;  // b*3+c, 0..23
  int o = blockIdx.x * 256 + threadIdx.x;
  if (o >= N16) return;
  int oy = o / 40, ox = o % 40;
  int ly, hy, lx, hx; float sy, sx; float wy[8], wx[8];
  taps1d(oy, &ly, &hy, &sy, wy);
  taps1d(ox, &lx, &hx, &sx, wx);
  const float* src = in + (size_t)map * 160 * 160;
  float acc = 0.f;
  for (int y = ly; y <= hy; ++y) {
    float a = 0.f;
    const float* row = src + y * 160;
    for (int x = lx; x <= hx; ++x) a += wx[x - lx] * row[x];
    acc += wy[y - ly] * a;
  }
  rz[map * N16 + o] = acc / (sy * sx);
}

// ------------- prep: sign counts (lan1/lan2) + row-normalize sample0 --------
__global__ void k_prep(const float* __restrict__ rz, float* __restrict__ F,
                       int* __restrict__ flags) {
  __shared__ int sp[256], sn[256];
  int blk = blockIdx.x;
  if (blk < 16) {
    int b = blk >> 1, c = blk & 1;
    const float* m = rz + (b * 3 + c) * N16;
    int cp = 0, cn = 0;
    for (int o = threadIdx.x; o < N16; o += 256) {
      float v = m[o];
      cp += (v > 0.f);
      cn += (v < 0.f);
    }
    sp[threadIdx.x] = cp; sn[threadIdx.x] = cn;
    __syncthreads();
    for (int s = 128; s > 0; s >>= 1) {
      if (threadIdx.x < s) {
        sp[threadIdx.x] += sp[threadIdx.x + s];
        sn[threadIdx.x] += sn[threadIdx.x + s];
      }
      __syncthreads();
    }
    if (threadIdx.x == 0) flags[blk] = (sp[0] == 0 || sn[0] == 0) ? 1 : 0;
  } else {
    int n = (blk - 16) * 256 + threadIdx.x;
    if (n < N16) {
      float x = rz[n], y = rz[N16 + n], z = rz[2 * N16 + n];
      float nrm = sqrtf(x * x + y * y + z * z);
      float s = 1.f / fmaxf(nrm, EPSF);
      F[n * 3 + 0] = x * s; F[n * 3 + 1] = y * s; F[n * 3 + 2] = z * s;
    }
  }
}

// ------------- degree: d_i = sum_j max(0, f_i . f_j); R = 1/sqrt(d) ---------
__global__ void k_degree(const float* __restrict__ F, float* __restrict__ R) {
  __shared__ float Fl[4800];
  __shared__ float red[256];
  for (int t = threadIdx.x; t < 4800; t += 256) Fl[t] = F[t];
  __syncthreads();
  int rl = threadIdx.x >> 4, jt = threadIdx.x & 15;
  int i = blockIdx.x * 16 + rl;
  float fx = Fl[i * 3], fy = Fl[i * 3 + 1], fz = Fl[i * 3 + 2];
  float s = 0.f;
  for (int j = jt; j < N16; j += 16) {
    float w = fx * Fl[j * 3] + fy * Fl[j * 3 + 1] + fz * Fl[j * 3 + 2];
    if (w > 0.f) s += w;
  }
  red[threadIdx.x] = s;
  __syncthreads();
  for (int st = 8; st > 0; st >>= 1) {
    if (jt < st) red[threadIdx.x] += red[threadIdx.x + st];
    __syncthreads();
  }
  if (jt == 0) {
    float d = red[threadIdx.x];
    if (d < EPSF) d = 1.f;
    R[i] = rsqrtf(d);
  }
}

// ------------- G = r_j * f_j; deterministic init of X0 ----------------------
__global__ void k_scale_init(const float* __restrict__ F, const float* __restrict__ R,
                             float* __restrict__ G, float* __restrict__ X0) {
  int n = blockIdx.x * 256 + threadIdx.x;
  if (n >= N16) return;
  float r = R[n];
  G[n * 3 + 0] = r * F[n * 3 + 0];
  G[n * 3 + 1] = r * F[n * 3 + 1];
  G[n * 3 + 2] = r * F[n * 3 + 2];
  unsigned base = (unsigned)n * 2654435761u;
  for (int k = 0; k < M; ++k) {
    unsigned u = base ^ ((unsigned)k * 0x9E3779B9u);
    u = u * 1664525u + 1013904223u;
    u ^= u >> 16; u *= 2246822519u; u ^= u >> 13;
    X0[n * M + k] = ((float)(u >> 8) * (1.f / 8388608.f)) - 1.f;
  }
}

// ------------- Xout = 0.5*(Xin + S Xin), S applied on the fly ---------------
__global__ void __launch_bounds__(256)
k_matvec(const float* __restrict__ F, const float* __restrict__ G,
         const float* __restrict__ R,
         const float* __restrict__ Xin, float* __restrict__ Xout) {
  __shared__ float Gl[4800];
  __shared__ float red[256 * 33];
  for (int t = threadIdx.x; t < 4800; t += 256) Gl[t] = G[t];
  int rl = threadIdx.x >> 4, jt = threadIdx.x & 15;
  int i = blockIdx.x * 16 + rl;
  float fx = F[i * 3], fy = F[i * 3 + 1], fz = F[i * 3 + 2];
  float acc[M];
#pragma unroll
  for (int k = 0; k < M; ++k) acc[k] = 0.f;
  __syncthreads();
  for (int j = jt; j < N16; j += 16) {
    float w = fx * Gl[j * 3] + fy * Gl[j * 3 + 1] + fz * Gl[j * 3 + 2];
    if (w > 0.f) {
      const float4* xr = (const float4*)(Xin + j * M);
#pragma unroll
      for (int q = 0; q < M / 4; ++q) {
        float4 v = xr[q];
        acc[4 * q + 0] += w * v.x;
        acc[4 * q + 1] += w * v.y;
        acc[4 * q + 2] += w * v.z;
        acc[4 * q + 3] += w * v.w;
      }
    }
  }
  float* myred = red + threadIdx.x * 33;
#pragma unroll
  for (int k = 0; k < M; ++k) myred[k] = acc[k];
  __syncthreads();
  for (int t = threadIdx.x; t < 16 * M; t += 256) {
    int row_l = t >> 5, k = t & 31;
    float s = 0.f;
    int base = (row_l * 16) * 33 + k;
#pragma unroll
    for (int q = 0; q < 16; ++q) s += red[base + q * 33];
    int ii = blockIdx.x * 16 + row_l;
    Xout[ii * M + k] = 0.5f * (Xin[ii * M + k] + R[ii] * s);
  }
}

// ------------- partial Gram: Gpart[blk] = (Xa chunk)^T (Xb chunk) -----------
__global__ void k_gram(const float* __restrict__ Xa, const float* __restrict__ Xb,
                       float* __restrict__ Gpart) {
  __shared__ float sA[64 * M], sB[64 * M];
  int j0 = blockIdx.x * 64;
  for (int t = threadIdx.x; t < 64 * M; t += 256) {
    sA[t] = Xa[j0 * M + t];
    sB[t] = Xb[j0 * M + t];
  }
  __syncthreads();
  int e0 = threadIdx.x * 4;
  for (int e = e0; e < e0 + 4; ++e) {
    int a = e >> 5, b = e & 31;
    float s = 0.f;
    for (int jl = 0; jl < 64; ++jl) s += sA[jl * M + a] * sB[jl * M + b];
    Gpart[blockIdx.x * 1024 + e] = s;
  }
}

// ------------- reduce Gram, Cholesky, invert L; Q[c*32+r] = Linv[r][c] ------
__global__ void k_cholinv(const float* __restrict__ Gpart, float* __restrict__ Q) {
  __shared__ float Gm[1024];
  __shared__ float Xs[32 * 33];
  int t = threadIdx.x;
  for (int e = t; e < 1024; e += 64) {
    float s = 0.f;
    for (int b = 0; b < 25; ++b) s += Gpart[b * 1024 + e];
    Gm[e] = s;
  }
  __syncthreads();
  for (int k = 0; k < 32; ++k) {
    if (t == 0) Gm[k * 32 + k] = sqrtf(fmaxf(Gm[k * 32 + k], 1e-30f));
    __syncthreads();
    float piv = Gm[k * 32 + k];
    if (t > k && t < 32) Gm[t * 32 + k] /= piv;
    __syncthreads();
    for (int i = k + 1; i < 32; ++i) {
      if (t < i - k) {
        int j = k + 1 + t;
        Gm[i * 32 + j] -= Gm[i * 32 + k] * Gm[j * 32 + k];
      }
    }
    __syncthreads();
  }
  if (t < 32) {
    int k = t;
    for (int i = 0; i < 32; ++i) {
      float x;
      if (i < k) {
        x = 0.f;
      } else {
        x = (i == k) ? 1.f : 0.f;
        for (int l = k; l < i; ++l) x -= Gm[i * 32 + l] * Xs[k * 33 + l];
        x /= Gm[i * 32 + i];
      }
      Xs[k * 33 + i] = x;
    }
  }
  __syncthreads();
  for (int e = t; e < 1024; e += 64) {
    int k = e >> 5, i = e & 31;
    Q[e] = Xs[k * 33 + i];  // Q[k*32+i] = Linv[i][k]
  }
}

// ------------- Xout = Xin * L^{-T} ------------------------------------------
__global__ void k_apply(const float* __restrict__ Xin, const float* __restrict__ Q,
                        float* __restrict__ Xout) {
  __shared__ float Qs[1024];
  for (int t = threadIdx.x; t < 1024; t += 256) Qs[t] = Q[t];
  __syncthreads();
  int idx = blockIdx.x * 256 + threadIdx.x;
  int j = idx >> 5, k = idx & 31;
  float s = 0.f;
  const float* xr = Xin + j * M;
  for (int l = 0; l <= k; ++l) s += xr[l] * Qs[l * 32 + k];  // Linv[k][l]
  Xout[idx] = s;
}

// ------------- Rayleigh-Ritz 32x32 Jacobi + final loss ----------------------
__global__ void k_rr(const float* __restrict__ Bpart, const int* __restrict__ flags,
                     const int* __restrict__ Kptr, float* __restrict__ out) {
  __shared__ float Braw[1024];
  __shared__ float Bs[32 * 33];
  __shared__ float cA[16], sA[16];
  __shared__ int pv[16], qv[16];
  __shared__ float evs[32], mu[32];
  int t = threadIdx.x;
  for (int e = t; e < 1024; e += 256) {
    float s = 0.f;
    for (int b = 0; b < 25; ++b) s += Bpart[b * 1024 + e];
    Braw[e] = s;
  }
  __syncthreads();
  for (int e = t; e < 1024; e += 256) {
    int i = e >> 5, j = e & 31;
    Bs[i * 33 + j] = 0.5f * (Braw[e] + Braw[j * 32 + i]);
  }
  __syncthreads();
  for (int sweep = 0; sweep < NSWEEP; ++sweep) {
    for (int r = 0; r < 31; ++r) {
      if (t < 16) {
        int p, q;
        if (t == 0) { p = 31; q = r % 31; }
        else { p = (r + t) % 31; q = (r + 31 - t) % 31; }
        float app = Bs[p * 33 + p], aqq = Bs[q * 33 + q], apq = Bs[p * 33 + q];
        float cc = 1.f, ss = 0.f;
        if (fabsf(apq) > 1e-20f) {
          float tau = (aqq - app) / (2.f * apq);
          float tt = (tau >= 0.f ? 1.f : -1.f) / (fabsf(tau) + sqrtf(1.f + tau * tau));
          cc = rsqrtf(1.f + tt * tt);
          ss = tt * cc;
        }
        cA[t] = cc; sA[t] = ss; pv[t] = p; qv[t] = q;
      }
      __syncthreads();
      for (int it = t; it < 512; it += 256) {  // columns: B <- B*J
        int m = it >> 5, i = it & 31;
        int p = pv[m], q = qv[m];
        float cc = cA[m], ss = sA[m];
        float bip = Bs[i * 33 + p], biq = Bs[i * 33 + q];
        Bs[i * 33 + p] = cc * bip - ss * biq;
        Bs[i * 33 + q] = ss * bip + cc * biq;
      }
      __syncthreads();
      for (int it = t; it < 512; it += 256) {  // rows: B <- J^T*B
        int m = it >> 5, j = it & 31;
        int p = pv[m], q = qv[m];
        float cc = cA[m], ss = sA[m];
        float bpj = Bs[p * 33 + j], bqj = Bs[q * 33 + j];
        Bs[p * 33 + j] = cc * bpj - ss * bqj;
        Bs[q * 33 + j] = ss * bpj + cc * bqj;
      }
      __syncthreads();
    }
  }
  if (t < 32) evs[t] = Bs[t * 33 + t];
  __syncthreads();
  if (t < 32) {
    float v = evs[t];
    int rank = 0;
    for (int j = 0; j < 32; ++j) {
      float u = evs[j];
      rank += (u > v) || (u == v && j < t);
    }
    mu[rank] = 2.f - 2.f * v;  // descending a -> ascending eigenvalues of Ln
  }
  __syncthreads();
  if (t == 0) {
    int K = Kptr ? *Kptr : 10;
    if (K < 1) K = 10;
    if (K > 32) K = 32;
    float t12 = 0.f, t13 = 0.f, t23 = 0.f;
    for (int b = 0; b < 8; ++b) {
      float f1 = flags[b * 2 + 0] ? 1.f : 0.f;
      float f2 = flags[b * 2 + 1] ? 1.f : 0.f;
      for (int k = 0; k < K; ++k) {
        float v1 = (k == 0) ? 0.f : (k == 1 ? f1 : 1.f);
        float v2 = (k == 0) ? 0.f : (k == 1 ? f2 : 1.f);
        float m3 = mu[k];
        t12 += (v1 - v2) * (v1 - v2);
        t13 += (v1 - m3) * (v1 - m3);
        t23 += (v2 - m3) * (v2 - m3);
      }
    }
    out[0] = 5.f * (t12 + t13 + t23) / (8.f * (float)K);
  }
}

extern "C" void kernel_launch(void* const* d_in, const int* in_sizes, int n_in,
                              void* d_out, int out_size, void* d_ws, size_t ws_size,
                              hipStream_t stream) {
  const float* feats = (const float*)d_in[0];
  const int* Kptr = (n_in > 1) ? (const int*)d_in[1] : nullptr;
  float* ws = (float*)d_ws;
  float* RZ = ws;                      // 38400
  float* F = ws + 38400;               // 4800
  float* G = ws + 43200;               // 4800
  float* R = ws + 48000;               // 1600
  int* FLAGS = (int*)(ws + 49600);     // 16 ints (64 floats reserved)
  float* X0 = ws + 49664;              // 51200
  float* X1 = ws + 100864;             // 51200
  float* GP = ws + 152064;             // 25600
  float* Q = ws + 177664;              // 1024

  k_resize<<<dim3(7, 24), 256, 0, stream>>>(feats, RZ);
  k_prep<<<23, 256, 0, stream>>>(RZ, F, FLAGS);
  k_degree<<<100, 256, 0, stream>>>(F, R);
  k_scale_init<<<7, 256, 0, stream>>>(F, R, G, X0);

  float* Xa = X0;
  float* Xb = X1;
  for (int outer = 0; outer < T_OUTER; ++outer) {
    for (int p = 0; p < P_INNER; ++p) {
      k_matvec<<<100, 256, 0, stream>>>(F, G, R, Xa, Xb);
      float* tmp = Xa; Xa = Xb; Xb = tmp;
    }
    k_gram<<<25, 256, 0, stream>>>(Xa, Xa, GP);
    k_cholinv<<<1, 64, 0, stream>>>(GP, Q);
    k_apply<<<200, 256, 0, stream>>>(Xa, Q, Xb);
    float* tmp = Xa; Xa = Xb; Xb = tmp;
  }
  // final Rayleigh-Ritz
  k_matvec<<<100, 256, 0, stream>>>(F, G, R, Xa, Xb);
  k_gram<<<25, 256, 0, stream>>>(Xa, Xb, GP);
  k_rr<<<1, 256, 0, stream>>>(GP, FLAGS, Kptr, (float*)d_out);
}

// Round 2
// 3398.294 us; speedup vs baseline: 3.4651x; 3.4651x over previous
//
#include <hip/hip_runtime.h>
#include <math.h>

#define N16 1600
#define M 32
#define T_OUTER 8
#define P_INNER 6
#define NSWEEP 10
#define EPSF 1e-12f
#define CH 320  // j-chunk staged in LDS per matvec step (5 chunks of 320)

// ---------------- resize (jax.image.resize bilinear, antialias=True) --------
__device__ inline void taps1d(int o, int* lo, int* hi, float* wsum, float w[8]) {
  int l = 4 * o - 2, h = 4 * o + 5;
  if (l < 0) l = 0;
  if (h > 159) h = 159;
  float c = 4.f * o + 1.5f, s = 0.f;
  for (int x = l; x <= h; ++x) {
    float ww = 1.f - fabsf((float)x - c) * 0.25f;
    w[x - l] = ww;
    s += ww;
  }
  *lo = l; *hi = h; *wsum = s;
}

__global__ void k_resize(const float* __restrict__ in, float* __restrict__ rz) {
  int map = blockIdx.y;  // b*3+c, 0..23
  int o = blockIdx.x * 256 + threadIdx.x;
  if (o >= N16) return;
  int oy = o / 40, ox = o % 40;
  int ly, hy, lx, hx; float sy, sx; float wy[8], wx[8];
  taps1d(oy, &ly, &hy, &sy, wy);
  taps1d(ox, &lx, &hx, &sx, wx);
  const float* src = in + (size_t)map * 160 * 160;
  float acc = 0.f;
  for (int y = ly; y <= hy; ++y) {
    float a = 0.f;
    const float* row = src + y * 160;
    for (int x = lx; x <= hx; ++x) a += wx[x - lx] * row[x];
    acc += wy[y - ly] * a;
  }
  rz[map * N16 + o] = acc / (sy * sx);
}

// ------------- prep: sign counts (lan1/lan2) + row-normalize sample0 --------
__global__ void k_prep(const float* __restrict__ rz, float* __restrict__ F,
                       int* __restrict__ flags) {
  __shared__ int sp[256], sn[256];
  int blk = blockIdx.x;
  if (blk < 16) {
    int b = blk >> 1, c = blk & 1;
    const float* m = rz + (b * 3 + c) * N16;
    int cp = 0, cn = 0;
    for (int o = threadIdx.x; o < N16; o += 256) {
      float v = m[o];
      cp += (v > 0.f);
      cn += (v < 0.f);
    }
    sp[threadIdx.x] = cp; sn[threadIdx.x] = cn;
    __syncthreads();
    for (int s = 128; s > 0; s >>= 1) {
      if (threadIdx.x < s) {
        sp[threadIdx.x] += sp[threadIdx.x + s];
        sn[threadIdx.x] += sn[threadIdx.x + s];
      }
      __syncthreads();
    }
    if (threadIdx.x == 0) flags[blk] = (sp[0] == 0 || sn[0] == 0) ? 1 : 0;
  } else {
    int n = (blk - 16) * 256 + threadIdx.x;
    if (n < N16) {
      float x = rz[n], y = rz[N16 + n], z = rz[2 * N16 + n];
      float nrm = sqrtf(x * x + y * y + z * z);
      float s = 1.f / fmaxf(nrm, EPSF);
      F[n * 3 + 0] = x * s; F[n * 3 + 1] = y * s; F[n * 3 + 2] = z * s;
    }
  }
}

// ------------- degree: d_i = sum_j max(0, f_i . f_j); R = 1/sqrt(d) ---------
__global__ void k_degree(const float* __restrict__ F, float* __restrict__ R) {
  __shared__ float Fl[4800];
  __shared__ float red[256];
  for (int t = threadIdx.x; t < 4800; t += 256) Fl[t] = F[t];
  __syncthreads();
  int rl = threadIdx.x >> 4, jt = threadIdx.x & 15;
  int i = blockIdx.x * 16 + rl;
  float fx = Fl[i * 3], fy = Fl[i * 3 + 1], fz = Fl[i * 3 + 2];
  float s = 0.f;
  for (int j = jt; j < N16; j += 16) {
    float w = fx * Fl[j * 3] + fy * Fl[j * 3 + 1] + fz * Fl[j * 3 + 2];
    if (w > 0.f) s += w;
  }
  red[threadIdx.x] = s;
  __syncthreads();
  for (int st = 8; st > 0; st >>= 1) {
    if (jt < st) red[threadIdx.x] += red[threadIdx.x + st];
    __syncthreads();
  }
  if (jt == 0) {
    float d = red[threadIdx.x];
    if (d < EPSF) d = 1.f;
    R[i] = rsqrtf(d);
  }
}

// ------------- G4 = {r_j * f_j, 0}; deterministic init of X0 ----------------
__global__ void k_scale_init(const float* __restrict__ F, const float* __restrict__ R,
                             float4* __restrict__ G4, float* __restrict__ X0) {
  int n = blockIdx.x * 256 + threadIdx.x;
  if (n >= N16) return;
  float r = R[n];
  float4 g;
  g.x = r * F[n * 3 + 0];
  g.y = r * F[n * 3 + 1];
  g.z = r * F[n * 3 + 2];
  g.w = 0.f;
  G4[n] = g;
  unsigned base = (unsigned)n * 2654435761u;
  for (int k = 0; k < M; ++k) {
    unsigned u = base ^ ((unsigned)k * 0x9E3779B9u);
    u = u * 1664525u + 1013904223u;
    u ^= u >> 16; u *= 2246822519u; u ^= u >> 13;
    X0[n * M + k] = ((float)(u >> 8) * (1.f / 8388608.f)) - 1.f;
  }
}

// ------------- Xout = 0.5*(Xin + S Xin) -------------------------------------
// thread = (row, k): i = blockIdx*8 + t>>5, k = t&31. No cross-thread reduce.
// X staged in LDS chunks of CH rows; G read as wave-uniform float4 (s_load).
__global__ void __launch_bounds__(256)
k_matvec(const float* __restrict__ F, const float4* __restrict__ G4,
         const float* __restrict__ R,
         const float* __restrict__ Xin, float* __restrict__ Xout) {
  __shared__ float Xs[CH * M];  // 40 KB
  const int t = threadIdx.x;
  const int i = blockIdx.x * 8 + (t >> 5);
  const int k = t & 31;
  const float fx = F[i * 3], fy = F[i * 3 + 1], fz = F[i * 3 + 2];
  float acc = 0.f;
  for (int c = 0; c < N16 / CH; ++c) {
    __syncthreads();
    // stage CH*M floats = 2560 float4, 10 per thread, coalesced
    const float4* srcX = (const float4*)(Xin + c * CH * M);
    float4* dstX = (float4*)Xs;
#pragma unroll
    for (int s = 0; s < (CH * M / 4) / 256; ++s) dstX[s * 256 + t] = srcX[s * 256 + t];
    __syncthreads();
    const int j0 = c * CH;
#pragma unroll 8
    for (int jj = 0; jj < CH; ++jj) {
      float4 g = G4[j0 + jj];  // wave-uniform address -> scalar load
      float w = fx * g.x + fy * g.y + fz * g.z;
      acc += fmaxf(w, 0.f) * Xs[jj * M + k];
    }
  }
  Xout[i * M + k] = 0.5f * (Xin[i * M + k] + R[i] * acc);
}

// ------------- partial Gram: Gpart[blk] = (Xa chunk)^T (Xb chunk) -----------
__global__ void k_gram(const float* __restrict__ Xa, const float* __restrict__ Xb,
                       float* __restrict__ Gpart) {
  __shared__ float sA[64 * M], sB[64 * M];
  int j0 = blockIdx.x * 64;
  for (int t = threadIdx.x; t < 64 * M; t += 256) {
    sA[t] = Xa[j0 * M + t];
    sB[t] = Xb[j0 * M + t];
  }
  __syncthreads();
  int e0 = threadIdx.x * 4;
  for (int e = e0; e < e0 + 4; ++e) {
    int a = e >> 5, b = e & 31;
    float s = 0.f;
    for (int jl = 0; jl < 64; ++jl) s += sA[jl * M + a] * sB[jl * M + b];
    Gpart[blockIdx.x * 1024 + e] = s;
  }
}

// ------------- reduce Gram, Cholesky, invert L; Q[c*32+r] = Linv[r][c] ------
__global__ void k_cholinv(const float* __restrict__ Gpart, float* __restrict__ Q) {
  __shared__ float Gm[1024];
  __shared__ float Xs[32 * 33];
  int t = threadIdx.x;
  for (int e = t; e < 1024; e += 64) {
    float s = 0.f;
    for (int b = 0; b < 25; ++b) s += Gpart[b * 1024 + e];
    Gm[e] = s;
  }
  __syncthreads();
  for (int k = 0; k < 32; ++k) {
    if (t == 0) Gm[k * 32 + k] = sqrtf(fmaxf(Gm[k * 32 + k], 1e-30f));
    __syncthreads();
    float piv = Gm[k * 32 + k];
    if (t > k && t < 32) Gm[t * 32 + k] /= piv;
    __syncthreads();
    for (int i = k + 1; i < 32; ++i) {
      if (t < i - k) {
        int j = k + 1 + t;
        Gm[i * 32 + j] -= Gm[i * 32 + k] * Gm[j * 32 + k];
      }
    }
    __syncthreads();
  }
  if (t < 32) {
    int k = t;
    for (int i = 0; i < 32; ++i) {
      float x;
      if (i < k) {
        x = 0.f;
      } else {
        x = (i == k) ? 1.f : 0.f;
        for (int l = k; l < i; ++l) x -= Gm[i * 32 + l] * Xs[k * 33 + l];
        x /= Gm[i * 32 + i];
      }
      Xs[k * 33 + i] = x;
    }
  }
  __syncthreads();
  for (int e = t; e < 1024; e += 64) {
    int k = e >> 5, i = e & 31;
    Q[e] = Xs[k * 33 + i];  // Q[k*32+i] = Linv[i][k]
  }
}

// ------------- Xout = Xin * L^{-T} ------------------------------------------
__global__ void k_apply(const float* __restrict__ Xin, const float* __restrict__ Q,
                        float* __restrict__ Xout) {
  __shared__ float Qs[1024];
  for (int t = threadIdx.x; t < 1024; t += 256) Qs[t] = Q[t];
  __syncthreads();
  int idx = blockIdx.x * 256 + threadIdx.x;
  int j = idx >> 5, k = idx & 31;
  float s = 0.f;
  const float* xr = Xin + j * M;
  for (int l = 0; l <= k; ++l) s += xr[l] * Qs[l * 32 + k];  // Linv[k][l]
  Xout[idx] = s;
}

// ------------- Rayleigh-Ritz 32x32 Jacobi + final loss ----------------------
__global__ void k_rr(const float* __restrict__ Bpart, const int* __restrict__ flags,
                     const int* __restrict__ Kptr, float* __restrict__ out) {
  __shared__ float Braw[1024];
  __shared__ float Bs[32 * 33];
  __shared__ float cA[16], sA[16];
  __shared__ int pv[16], qv[16];
  __shared__ float evs[32], mu[32];
  int t = threadIdx.x;
  for (int e = t; e < 1024; e += 256) {
    float s = 0.f;
    for (int b = 0; b < 25; ++b) s += Bpart[b * 1024 + e];
    Braw[e] = s;
  }
  __syncthreads();
  for (int e = t; e < 1024; e += 256) {
    int i = e >> 5, j = e & 31;
    Bs[i * 33 + j] = 0.5f * (Braw[e] + Braw[j * 32 + i]);
  }
  __syncthreads();
  for (int sweep = 0; sweep < NSWEEP; ++sweep) {
    for (int r = 0; r < 31; ++r) {
      if (t < 16) {
        int p, q;
        if (t == 0) { p = 31; q = r % 31; }
        else { p = (r + t) % 31; q = (r + 31 - t) % 31; }
        float app = Bs[p * 33 + p], aqq = Bs[q * 33 + q], apq = Bs[p * 33 + q];
        float cc = 1.f, ss = 0.f;
        if (fabsf(apq) > 1e-20f) {
          float tau = (aqq - app) / (2.f * apq);
          float tt = (tau >= 0.f ? 1.f : -1.f) / (fabsf(tau) + sqrtf(1.f + tau * tau));
          cc = rsqrtf(1.f + tt * tt);
          ss = tt * cc;
        }
        cA[t] = cc; sA[t] = ss; pv[t] = p; qv[t] = q;
      }
      __syncthreads();
      for (int it = t; it < 512; it += 256) {  // columns: B <- B*J
        int m = it >> 5, i = it & 31;
        int p = pv[m], q = qv[m];
        float cc = cA[m], ss = sA[m];
        float bip = Bs[i * 33 + p], biq = Bs[i * 33 + q];
        Bs[i * 33 + p] = cc * bip - ss * biq;
        Bs[i * 33 + q] = ss * bip + cc * biq;
      }
      __syncthreads();
      for (int it = t; it < 512; it += 256) {  // rows: B <- J^T*B
        int m = it >> 5, j = it & 31;
        int p = pv[m], q = qv[m];
        float cc = cA[m], ss = sA[m];
        float bpj = Bs[p * 33 + j], bqj = Bs[q * 33 + j];
        Bs[p * 33 + j] = cc * bpj - ss * bqj;
        Bs[q * 33 + j] = ss * bpj + cc * bqj;
      }
      __syncthreads();
    }
  }
  if (t < 32) evs[t] = Bs[t * 33 + t];
  __syncthreads();
  if (t < 32) {
    float v = evs[t];
    int rank = 0;
    for (int j = 0; j < 32; ++j) {
      float u = evs[j];
      rank += (u > v) || (u == v && j < t);
    }
    mu[rank] = 2.f - 2.f * v;  // descending a -> ascending eigenvalues of Ln
  }
  __syncthreads();
  if (t == 0) {
    int K = Kptr ? *Kptr : 10;
    if (K < 1) K = 10;
    if (K > 32) K = 32;
    float t12 = 0.f, t13 = 0.f, t23 = 0.f;
    for (int b = 0; b < 8; ++b) {
      float f1 = flags[b * 2 + 0] ? 1.f : 0.f;
      float f2 = flags[b * 2 + 1] ? 1.f : 0.f;
      for (int k = 0; k < K; ++k) {
        float v1 = (k == 0) ? 0.f : (k == 1 ? f1 : 1.f);
        float v2 = (k == 0) ? 0.f : (k == 1 ? f2 : 1.f);
        float m3 = mu[k];
        t12 += (v1 - v2) * (v1 - v2);
        t13 += (v1 - m3) * (v1 - m3);
        t23 += (v2 - m3) * (v2 - m3);
      }
    }
    out[0] = 5.f * (t12 + t13 + t23) / (8.f * (float)K);
  }
}

extern "C" void kernel_launch(void* const* d_in, const int* in_sizes, int n_in,
                              void* d_out, int out_size, void* d_ws, size_t ws_size,
                              hipStream_t stream) {
  const float* feats = (const float*)d_in[0];
  const int* Kptr = (n_in > 1) ? (const int*)d_in[1] : nullptr;
  float* ws = (float*)d_ws;
  // layout (floats). RZ region is dead after k_prep; GP/Q overlay it.
  float* RZ = ws;                      // 38400 (24 maps x 1600)
  float* GP = ws;                      // 25600 (25 x 1024) — overlays RZ
  float* Q  = ws + 25600;              // 1024          — overlays RZ
  float* F  = ws + 38400;              // 4800
  float4* G4 = (float4*)(ws + 43200);  // 1600 float4 = 6400 floats (16B aligned)
  float* R  = ws + 49600;              // 1600
  int* FLAGS = (int*)(ws + 51200);     // 16 ints (64 floats reserved)
  float* X0 = ws + 51264;              // 51200
  float* X1 = ws + 102464;             // 51200  (end: 153664 floats = 615 KB)

  k_resize<<<dim3(7, 24), 256, 0, stream>>>(feats, RZ);
  k_prep<<<23, 256, 0, stream>>>(RZ, F, FLAGS);
  k_degree<<<100, 256, 0, stream>>>(F, R);
  k_scale_init<<<7, 256, 0, stream>>>(F, R, G4, X0);

  float* Xa = X0;
  float* Xb = X1;
  for (int outer = 0; outer < T_OUTER; ++outer) {
    for (int p = 0; p < P_INNER; ++p) {
      k_matvec<<<200, 256, 0, stream>>>(F, G4, R, Xa, Xb);
      float* tmp = Xa; Xa = Xb; Xb = tmp;
    }
    k_gram<<<25, 256, 0, stream>>>(Xa, Xa, GP);
    k_cholinv<<<1, 64, 0, stream>>>(GP, Q);
    k_apply<<<200, 256, 0, stream>>>(Xa, Q, Xb);
    float* tmp = Xa; Xa = Xb; Xb = tmp;
  }
  // final Rayleigh-Ritz
  k_matvec<<<200, 256, 0, stream>>>(F, G4, R, Xa, Xb);
  k_gram<<<25, 256, 0, stream>>>(Xa, Xb, GP);
  k_rr<<<1, 256, 0, stream>>>(GP, FLAGS, Kptr, (float*)d_out);
}

// Round 3
// 2095.276 us; speedup vs baseline: 5.6200x; 1.6219x over previous
//
#include <hip/hip_runtime.h>
#include <math.h>

#define N16 1600
#define M 32
#define T_OUTER 4
#define P_INNER 6
#define NSWEEP 7
#define EPSF 1e-12f
#define CH2 160  // j-chunk of X staged in LDS (10 chunks)

// ---------------- resize (jax.image.resize bilinear, antialias=True) --------
__device__ inline void taps1d(int o, int* lo, int* hi, float* wsum, float w[8]) {
  int l = 4 * o - 2, h = 4 * o + 5;
  if (l < 0) l = 0;
  if (h > 159) h = 159;
  float c = 4.f * o + 1.5f, s = 0.f;
  for (int x = l; x <= h; ++x) {
    float ww = 1.f - fabsf((float)x - c) * 0.25f;
    w[x - l] = ww;
    s += ww;
  }
  *lo = l; *hi = h; *wsum = s;
}

__global__ void k_resize(const float* __restrict__ in, float* __restrict__ rz) {
  int map = blockIdx.y;  // b*3+c, 0..23
  int o = blockIdx.x * 256 + threadIdx.x;
  if (o >= N16) return;
  int oy = o / 40, ox = o % 40;
  int ly, hy, lx, hx; float sy, sx; float wy[8], wx[8];
  taps1d(oy, &ly, &hy, &sy, wy);
  taps1d(ox, &lx, &hx, &sx, wx);
  const float* src = in + (size_t)map * 160 * 160;
  float acc = 0.f;
  for (int y = ly; y <= hy; ++y) {
    float a = 0.f;
    const float* row = src + y * 160;
    for (int x = lx; x <= hx; ++x) a += wx[x - lx] * row[x];
    acc += wy[y - ly] * a;
  }
  rz[map * N16 + o] = acc / (sy * sx);
}

// ------------- prep: sign counts (lan1/lan2) + row-normalize sample0 --------
__global__ void k_prep(const float* __restrict__ rz, float* __restrict__ F,
                       int* __restrict__ flags) {
  __shared__ int sp[256], sn[256];
  int blk = blockIdx.x;
  if (blk < 16) {
    int b = blk >> 1, c = blk & 1;
    const float* m = rz + (b * 3 + c) * N16;
    int cp = 0, cn = 0;
    for (int o = threadIdx.x; o < N16; o += 256) {
      float v = m[o];
      cp += (v > 0.f);
      cn += (v < 0.f);
    }
    sp[threadIdx.x] = cp; sn[threadIdx.x] = cn;
    __syncthreads();
    for (int s = 128; s > 0; s >>= 1) {
      if (threadIdx.x < s) {
        sp[threadIdx.x] += sp[threadIdx.x + s];
        sn[threadIdx.x] += sn[threadIdx.x + s];
      }
      __syncthreads();
    }
    if (threadIdx.x == 0) flags[blk] = (sp[0] == 0 || sn[0] == 0) ? 1 : 0;
  } else {
    int n = (blk - 16) * 256 + threadIdx.x;
    if (n < N16) {
      float x = rz[n], y = rz[N16 + n], z = rz[2 * N16 + n];
      float nrm = sqrtf(x * x + y * y + z * z);
      float s = 1.f / fmaxf(nrm, EPSF);
      F[n * 3 + 0] = x * s; F[n * 3 + 1] = y * s; F[n * 3 + 2] = z * s;
    }
  }
}

// ------------- degree: d_i = sum_j max(0, f_i . f_j); R = 1/sqrt(d) ---------
__global__ void k_degree(const float* __restrict__ F, float* __restrict__ R) {
  __shared__ float Fl[4800];
  __shared__ float red[256];
  for (int t = threadIdx.x; t < 4800; t += 256) Fl[t] = F[t];
  __syncthreads();
  int rl = threadIdx.x >> 4, jt = threadIdx.x & 15;
  int i = blockIdx.x * 16 + rl;
  float fx = Fl[i * 3], fy = Fl[i * 3 + 1], fz = Fl[i * 3 + 2];
  float s = 0.f;
  for (int j = jt; j < N16; j += 16) {
    float w = fx * Fl[j * 3] + fy * Fl[j * 3 + 1] + fz * Fl[j * 3 + 2];
    if (w > 0.f) s += w;
  }
  red[threadIdx.x] = s;
  __syncthreads();
  for (int st = 8; st > 0; st >>= 1) {
    if (jt < st) red[threadIdx.x] += red[threadIdx.x + st];
    __syncthreads();
  }
  if (jt == 0) {
    float d = red[threadIdx.x];
    if (d < EPSF) d = 1.f;
    R[i] = rsqrtf(d);
  }
}

// ------------- G4 = {r_j * f_j, 0}; deterministic init of X0 ----------------
__global__ void k_scale_init(const float* __restrict__ F, const float* __restrict__ R,
                             float4* __restrict__ G4, float* __restrict__ X0) {
  int n = blockIdx.x * 256 + threadIdx.x;
  if (n >= N16) return;
  float r = R[n];
  float4 g;
  g.x = r * F[n * 3 + 0];
  g.y = r * F[n * 3 + 1];
  g.z = r * F[n * 3 + 2];
  g.w = 0.f;
  G4[n] = g;
  unsigned base = (unsigned)n * 2654435761u;
  for (int k = 0; k < M; ++k) {
    unsigned u = base ^ ((unsigned)k * 0x9E3779B9u);
    u = u * 1664525u + 1013904223u;
    u ^= u >> 16; u *= 2246822519u; u ^= u >> 13;
    X0[n * M + k] = ((float)(u >> 8) * (1.f / 8388608.f)) - 1.f;
  }
}

// ------------- Xout = 0.5*(Xin + S Xin) -------------------------------------
// thread=(row,k). G fully staged in LDS (broadcast b128 reads), X staged in
// LDS chunks. No scalar-load chains, no branches. VALU-bound ~10 cyc/j.
__global__ void __launch_bounds__(256)
k_matvec(const float* __restrict__ F, const float4* __restrict__ G4,
         const float* __restrict__ R,
         const float* __restrict__ Xin, float* __restrict__ Xout) {
  __shared__ float4 Gs[N16];      // 25.6 KB
  __shared__ float Xs[CH2 * M];   // 20 KB
  const int t = threadIdx.x;
  for (int s = t; s < N16; s += 256) Gs[s] = G4[s];
  const int i = blockIdx.x * 8 + (t >> 5);
  const int k = t & 31;
  const float fx = F[i * 3], fy = F[i * 3 + 1], fz = F[i * 3 + 2];
  const float xik = Xin[i * M + k];
  float acc = 0.f;
  for (int c = 0; c < N16 / CH2; ++c) {
    __syncthreads();
    const float4* srcX = (const float4*)(Xin + c * CH2 * M);
    float4* dstX = (float4*)Xs;
#pragma unroll
    for (int s = 0; s < (CH2 * M / 4) / 256; ++s) dstX[s * 256 + t] = srcX[s * 256 + t];
    __syncthreads();
#pragma unroll 4
    for (int jj = 0; jj < CH2; ++jj) {
      float4 g = Gs[c * CH2 + jj];  // LDS broadcast (all lanes same addr)
      float w = fmaxf(fx * g.x + fy * g.y + fz * g.z, 0.f);
      acc += w * Xs[jj * M + k];
    }
  }
  Xout[i * M + k] = 0.5f * (xik + R[i] * acc);
}

// ------------- partial Gram: Gpart[blk] = (Xa chunk)^T (Xb chunk) -----------
__global__ void k_gram(const float* __restrict__ Xa, const float* __restrict__ Xb,
                       float* __restrict__ Gpart) {
  __shared__ float sA[64 * M], sB[64 * M];
  int j0 = blockIdx.x * 64;
  for (int t = threadIdx.x; t < 64 * M; t += 256) {
    sA[t] = Xa[j0 * M + t];
    sB[t] = Xb[j0 * M + t];
  }
  __syncthreads();
  int e0 = threadIdx.x * 4;
  for (int e = e0; e < e0 + 4; ++e) {
    int a = e >> 5, b = e & 31;
    float s = 0.f;
    for (int jl = 0; jl < 64; ++jl) s += sA[jl * M + a] * sB[jl * M + b];
    Gpart[blockIdx.x * 1024 + e] = s;
  }
}

// ------------- reduce Gram, Cholesky, invert L; Q[c*32+r] = Linv[r][c] ------
__global__ void k_cholinv(const float* __restrict__ Gpart, float* __restrict__ Q) {
  __shared__ float Gm[1024];
  __shared__ float Xs[32 * 33];
  int t = threadIdx.x;
  for (int e = t; e < 1024; e += 64) {
    float s = 0.f;
    for (int b = 0; b < 25; ++b) s += Gpart[b * 1024 + e];
    Gm[e] = s;
  }
  __syncthreads();
  for (int k = 0; k < 32; ++k) {
    if (t == 0) Gm[k * 32 + k] = sqrtf(fmaxf(Gm[k * 32 + k], 1e-30f));
    __syncthreads();
    float piv = Gm[k * 32 + k];
    if (t > k && t < 32) Gm[t * 32 + k] /= piv;
    __syncthreads();
    for (int i = k + 1; i < 32; ++i) {
      if (t < i - k) {
        int j = k + 1 + t;
        Gm[i * 32 + j] -= Gm[i * 32 + k] * Gm[j * 32 + k];
      }
    }
    __syncthreads();
  }
  if (t < 32) {
    int k = t;
    for (int i = 0; i < 32; ++i) {
      float x;
      if (i < k) {
        x = 0.f;
      } else {
        x = (i == k) ? 1.f : 0.f;
        for (int l = k; l < i; ++l) x -= Gm[i * 32 + l] * Xs[k * 33 + l];
        x /= Gm[i * 32 + i];
      }
      Xs[k * 33 + i] = x;
    }
  }
  __syncthreads();
  for (int e = t; e < 1024; e += 64) {
    int k = e >> 5, i = e & 31;
    Q[e] = Xs[k * 33 + i];  // Q[k*32+i] = Linv[i][k]
  }
}

// ------------- Xout = Xin * L^{-T} ------------------------------------------
__global__ void k_apply(const float* __restrict__ Xin, const float* __restrict__ Q,
                        float* __restrict__ Xout) {
  __shared__ float Qs[1024];
  for (int t = threadIdx.x; t < 1024; t += 256) Qs[t] = Q[t];
  __syncthreads();
  int idx = blockIdx.x * 256 + threadIdx.x;
  int j = idx >> 5, k = idx & 31;
  float s = 0.f;
  const float* xr = Xin + j * M;
  for (int l = 0; l <= k; ++l) s += xr[l] * Qs[l * 32 + k];  // Linv[k][l]
  Xout[idx] = s;
}

// ------------- Rayleigh-Ritz: fused parallel Jacobi (2 barriers/round) ------
// 128 threads (2 waves). Disjoint Givens rotations commute, so the full
// two-sided round J^T B J is computed elementwise (4 reads) into a second
// buffer. Pair membership per (round,index) precomputed once.
__global__ void __launch_bounds__(128)
k_rr(const float* __restrict__ Bpart, const int* __restrict__ flags,
     const int* __restrict__ Kptr, float* __restrict__ out) {
  __shared__ float B0[32 * 33], B1[32 * 33];
  __shared__ float Braw[1024];
  __shared__ float cA[16], sA[16];
  __shared__ int pv[16], qv[16];
  __shared__ int mapA[31 * 32];  // m | side<<4
  __shared__ float evs[32], mu[32];
  const int t = threadIdx.x;
  // reduce partial Grams, symmetrize
  for (int e = t; e < 1024; e += 128) {
    float s = 0.f;
    for (int b = 0; b < 25; ++b) s += Bpart[b * 1024 + e];
    Braw[e] = s;
  }
  __syncthreads();
  for (int e = t; e < 1024; e += 128) {
    int i = e >> 5, j = e & 31;
    B0[i * 33 + j] = 0.5f * (Braw[e] + Braw[j * 32 + i]);
  }
  // precompute round-robin pair membership: round r, index i -> (pair m, side)
  for (int idx = t; idx < 31 * 32; idx += 128) {
    int r = idx >> 5, i = idx & 31;
    int m, sd;
    if (i == 31) { m = 0; sd = 0; }
    else {
      int d = i - r; if (d < 0) d += 31;
      if (d == 0) { m = 0; sd = 1; }
      else if (d <= 15) { m = d; sd = 0; }
      else { m = 31 - d; sd = 1; }
    }
    mapA[idx] = m | (sd << 4);
  }
  __syncthreads();
  const int ROUNDS = NSWEEP * 31;
  for (int rr = 0; rr < ROUNDS; ++rr) {
    const int r = rr % 31;
    float* cur = (rr & 1) ? B1 : B0;
    float* nxt = (rr & 1) ? B0 : B1;
    if (t < 16) {
      int p, q;
      if (t == 0) { p = 31; q = r; }
      else { p = (r + t) % 31; q = (r + 31 - t) % 31; }
      float app = cur[p * 33 + p], aqq = cur[q * 33 + q], apq = cur[p * 33 + q];
      float cc = 1.f, ss = 0.f;
      if (fabsf(apq) > 1e-20f) {
        float tau = (aqq - app) / (2.f * apq);
        float tt = (tau >= 0.f ? 1.f : -1.f) / (fabsf(tau) + sqrtf(1.f + tau * tau));
        cc = rsqrtf(1.f + tt * tt);
        ss = tt * cc;
      }
      cA[t] = cc; sA[t] = ss; pv[t] = p; qv[t] = q;
    }
    __syncthreads();
    {
      const int j = t & 31;
      const int mj = mapA[r * 32 + j];
      const int mb = mj & 15, sb = mj >> 4;
      const int pb = pv[mb], qb = qv[mb];
      const float cb = cA[mb], ssb = sA[mb];
#pragma unroll
      for (int s = 0; s < 8; ++s) {
        const int i = (t >> 5) + 4 * s;
        const int mi = mapA[r * 32 + i];
        const int ma = mi & 15, sa = mi >> 4;
        const int pa = pv[ma], qa = qv[ma];
        const float ca = cA[ma], ssa = sA[ma];
        float vpp = cur[pa * 33 + pb], vpq = cur[pa * 33 + qb];
        float vqp = cur[qa * 33 + pb], vqq = cur[qa * 33 + qb];
        float wp = sb ? (ssb * vpp + cb * vpq) : (cb * vpp - ssb * vpq);
        float wq = sb ? (ssb * vqp + cb * vqq) : (cb * vqp - ssb * vqq);
        nxt[i * 33 + j] = sa ? (ssa * wp + ca * wq) : (ca * wp - ssa * wq);
      }
    }
    __syncthreads();
  }
  float* fin = (ROUNDS & 1) ? B1 : B0;
  if (t < 32) evs[t] = fin[t * 33 + t];
  __syncthreads();
  if (t < 32) {
    float v = evs[t];
    int rank = 0;
    for (int j = 0; j < 32; ++j) {
      float u = evs[j];
      rank += (u > v) || (u == v && j < t);
    }
    mu[rank] = 2.f - 2.f * v;  // descending A-eigs -> ascending eigs of Ln
  }
  __syncthreads();
  if (t == 0) {
    int K = Kptr ? *Kptr : 10;
    if (K < 1) K = 10;
    if (K > 32) K = 32;
    float t12 = 0.f, t13 = 0.f, t23 = 0.f;
    for (int b = 0; b < 8; ++b) {
      float f1 = flags[b * 2 + 0] ? 1.f : 0.f;
      float f2 = flags[b * 2 + 1] ? 1.f : 0.f;
      for (int k = 0; k < K; ++k) {
        float v1 = (k == 0) ? 0.f : (k == 1 ? f1 : 1.f);
        float v2 = (k == 0) ? 0.f : (k == 1 ? f2 : 1.f);
        float m3 = mu[k];
        t12 += (v1 - v2) * (v1 - v2);
        t13 += (v1 - m3) * (v1 - m3);
        t23 += (v2 - m3) * (v2 - m3);
      }
    }
    out[0] = 5.f * (t12 + t13 + t23) / (8.f * (float)K);
  }
}

extern "C" void kernel_launch(void* const* d_in, const int* in_sizes, int n_in,
                              void* d_out, int out_size, void* d_ws, size_t ws_size,
                              hipStream_t stream) {
  const float* feats = (const float*)d_in[0];
  const int* Kptr = (n_in > 1) ? (const int*)d_in[1] : nullptr;
  float* ws = (float*)d_ws;
  // layout (floats). RZ region is dead after k_prep; GP/Q overlay it.
  float* RZ = ws;                      // 38400 (24 maps x 1600)
  float* GP = ws;                      // 25600 (25 x 1024) — overlays RZ
  float* Q  = ws + 25600;              // 1024          — overlays RZ
  float* F  = ws + 38400;              // 4800
  float4* G4 = (float4*)(ws + 43200);  // 1600 float4 (16B aligned)
  float* R  = ws + 49600;              // 1600
  int* FLAGS = (int*)(ws + 51200);     // 16 ints (64 floats reserved)
  float* X0 = ws + 51264;              // 51200
  float* X1 = ws + 102464;             // 51200  (end: 153664 floats = 615 KB)

  k_resize<<<dim3(7, 24), 256, 0, stream>>>(feats, RZ);
  k_prep<<<23, 256, 0, stream>>>(RZ, F, FLAGS);
  k_degree<<<100, 256, 0, stream>>>(F, R);
  k_scale_init<<<7, 256, 0, stream>>>(F, R, G4, X0);

  float* Xa = X0;
  float* Xb = X1;
  for (int outer = 0; outer < T_OUTER; ++outer) {
    for (int p = 0; p < P_INNER; ++p) {
      k_matvec<<<200, 256, 0, stream>>>(F, G4, R, Xa, Xb);
      float* tmp = Xa; Xa = Xb; Xb = tmp;
    }
    k_gram<<<25, 256, 0, stream>>>(Xa, Xa, GP);
    k_cholinv<<<1, 64, 0, stream>>>(GP, Q);
    k_apply<<<200, 256, 0, stream>>>(Xa, Q, Xb);
    float* tmp = Xa; Xa = Xb; Xb = tmp;
  }
  // final Rayleigh-Ritz
  k_matvec<<<200, 256, 0, stream>>>(F, G4, R, Xa, Xb);
  k_gram<<<25, 256, 0, stream>>>(Xa, Xb, GP);
  k_rr<<<1, 128, 0, stream>>>(GP, FLAGS, Kptr, (float*)d_out);
}

// Round 4
// 1496.638 us; speedup vs baseline: 7.8680x; 1.4000x over previous
//
#include <hip/hip_runtime.h>
#include <math.h>

#define N16 1600
#define M 32
#define T_OUTER 4
#define P_INNER 6
#define EPSF 1e-12f
#define NPART 4
#define JR (N16 / NPART)  // 400 rows of j per part
#define CH 200            // j-rows staged in LDS per chunk (2 chunks/part)

// ---------------- wave-wide butterfly reductions (64 lanes) -----------------
__device__ inline float wred(float v) {
#pragma unroll
  for (int o = 32; o; o >>= 1) v += __shfl_xor(v, o, 64);
  return v;
}
__device__ inline float wredmin(float v) {
#pragma unroll
  for (int o = 32; o; o >>= 1) v = fminf(v, __shfl_xor(v, o, 64));
  return v;
}
__device__ inline float wredmax(float v) {
#pragma unroll
  for (int o = 32; o; o >>= 1) v = fmaxf(v, __shfl_xor(v, o, 64));
  return v;
}

// ---------------- resize (jax.image.resize bilinear, antialias=True) --------
__device__ inline void taps1d(int o, int* lo, int* hi, float* wsum, float w[8]) {
  int l = 4 * o - 2, h = 4 * o + 5;
  if (l < 0) l = 0;
  if (h > 159) h = 159;
  float c = 4.f * o + 1.5f, s = 0.f;
  for (int x = l; x <= h; ++x) {
    float ww = 1.f - fabsf((float)x - c) * 0.25f;
    w[x - l] = ww;
    s += ww;
  }
  *lo = l; *hi = h; *wsum = s;
}

__global__ void k_resize(const float* __restrict__ in, float* __restrict__ rz) {
  int map = blockIdx.y;  // b*3+c, 0..23
  int o = blockIdx.x * 256 + threadIdx.x;
  if (o >= N16) return;
  int oy = o / 40, ox = o % 40;
  int ly, hy, lx, hx; float sy, sx; float wy[8], wx[8];
  taps1d(oy, &ly, &hy, &sy, wy);
  taps1d(ox, &lx, &hx, &sx, wx);
  const float* src = in + (size_t)map * 160 * 160;
  float acc = 0.f;
  for (int y = ly; y <= hy; ++y) {
    float a = 0.f;
    const float* row = src + y * 160;
    for (int x = lx; x <= hx; ++x) a += wx[x - lx] * row[x];
    acc += wy[y - ly] * a;
  }
  rz[map * N16 + o] = acc / (sy * sx);
}

// ------------- prep: sign counts (lan1/lan2) + row-normalize sample0 --------
__global__ void k_prep(const float* __restrict__ rz, float* __restrict__ F,
                       int* __restrict__ flags) {
  __shared__ int sp[256], sn[256];
  int blk = blockIdx.x;
  if (blk < 16) {
    int b = blk >> 1, c = blk & 1;
    const float* m = rz + (b * 3 + c) * N16;
    int cp = 0, cn = 0;
    for (int o = threadIdx.x; o < N16; o += 256) {
      float v = m[o];
      cp += (v > 0.f);
      cn += (v < 0.f);
    }
    sp[threadIdx.x] = cp; sn[threadIdx.x] = cn;
    __syncthreads();
    for (int s = 128; s > 0; s >>= 1) {
      if (threadIdx.x < s) {
        sp[threadIdx.x] += sp[threadIdx.x + s];
        sn[threadIdx.x] += sn[threadIdx.x + s];
      }
      __syncthreads();
    }
    if (threadIdx.x == 0) flags[blk] = (sp[0] == 0 || sn[0] == 0) ? 1 : 0;
  } else {
    int n = (blk - 16) * 256 + threadIdx.x;
    if (n < N16) {
      float x = rz[n], y = rz[N16 + n], z = rz[2 * N16 + n];
      float nrm = sqrtf(x * x + y * y + z * z);
      float s = 1.f / fmaxf(nrm, EPSF);
      F[n * 3 + 0] = x * s; F[n * 3 + 1] = y * s; F[n * 3 + 2] = z * s;
    }
  }
}

// ------------- degree + G4 + X0 init (fused) --------------------------------
__global__ void k_degree(const float* __restrict__ F, float* __restrict__ R,
                         float4* __restrict__ G4, float* __restrict__ X0) {
  __shared__ float Fl[4800];
  __shared__ float red[256];
  for (int t = threadIdx.x; t < 4800; t += 256) Fl[t] = F[t];
  __syncthreads();
  int rl = threadIdx.x >> 4, jt = threadIdx.x & 15;
  int i = blockIdx.x * 16 + rl;
  float fx = Fl[i * 3], fy = Fl[i * 3 + 1], fz = Fl[i * 3 + 2];
  float s = 0.f;
  for (int j = jt; j < N16; j += 16) {
    float w = fx * Fl[j * 3] + fy * Fl[j * 3 + 1] + fz * Fl[j * 3 + 2];
    if (w > 0.f) s += w;
  }
  red[threadIdx.x] = s;
  __syncthreads();
  for (int st = 8; st > 0; st >>= 1) {
    if (jt < st) red[threadIdx.x] += red[threadIdx.x + st];
    __syncthreads();
  }
  if (jt == 0) {
    float d = red[threadIdx.x];
    if (d < EPSF) d = 1.f;
    float r = rsqrtf(d);
    R[i] = r;
    float4 g; g.x = r * fx; g.y = r * fy; g.z = r * fz; g.w = 0.f;
    G4[i] = g;
  }
  // deterministic X0 init for this block's 16 rows (16*32 = 512 elements)
  for (int e = threadIdx.x; e < 512; e += 256) {
    int n = blockIdx.x * 16 + (e >> 5);
    int k = e & 31;
    unsigned u = ((unsigned)n * 2654435761u) ^ ((unsigned)k * 0x9E3779B9u);
    u = u * 1664525u + 1013904223u;
    u ^= u >> 16; u *= 2246822519u; u ^= u >> 13;
    X0[n * M + k] = ((float)(u >> 8) * (1.f / 8388608.f)) - 1.f;
  }
}

// ------------- Xout_part = 0.5*(Xin/np + S_part Xin) ------------------------
// grid (200, npout). Input X given as npin stacked partial buffers (sum = X).
// Fallback npout==1: block loops over all 4 j-parts internally.
__global__ void __launch_bounds__(256)
k_matvec(const float* __restrict__ F, const float4* __restrict__ G4,
         const float* __restrict__ R, const float* __restrict__ XinB, int npin,
         float* __restrict__ XoutB, int npout, float inv_np) {
  __shared__ float4 Gs[JR];
  __shared__ float Xs[CH * M];
  const int t = threadIdx.x;
  const int i = blockIdx.x * 8 + (t >> 5);
  const int k = t & 31;
  const float fx = F[i * 3], fy = F[i * 3 + 1], fz = F[i * 3 + 2];
  float xik = 0.f;
  for (int p = 0; p < npin; ++p) xik += XinB[p * (N16 * M) + i * M + k];
  float acc = 0.f;
  const int pd = NPART / npout;  // parts handled per block
  const int p0 = blockIdx.y * pd;
  for (int part = p0; part < p0 + pd; ++part) {
    const int jlo = part * JR;
    __syncthreads();
    for (int s = t; s < JR; s += 256) Gs[s] = G4[jlo + s];
    for (int c = 0; c < JR / CH; ++c) {
      __syncthreads();
      const int base = (jlo + c * CH) * M;
      for (int s = t; s < CH * M / 4; s += 256) {
        const float4* pp = (const float4*)(XinB + base);
        float4 v = pp[s];
        for (int p = 1; p < npin; ++p) {
          float4 a = ((const float4*)(XinB + p * (N16 * M) + base))[s];
          v.x += a.x; v.y += a.y; v.z += a.z; v.w += a.w;
        }
        ((float4*)Xs)[s] = v;
      }
      __syncthreads();
      const int g0 = c * CH;
#pragma unroll 8
      for (int jj = 0; jj < CH; ++jj) {
        float4 g = Gs[g0 + jj];  // broadcast (all lanes same addr)
        float w = fmaxf(fx * g.x + fy * g.y + fz * g.z, 0.f);
        acc += w * Xs[jj * M + k];
      }
    }
  }
  XoutB[blockIdx.y * (N16 * M) + i * M + k] = 0.5f * (xik * inv_np + R[i] * acc);
}

// ------------- partial Gram over 64-row slabs -------------------------------
__global__ void k_gram(const float* __restrict__ XaB, int npa,
                       const float* __restrict__ XbB, int npb,
                       float* __restrict__ Gpart) {
  __shared__ float sA[64 * M], sB[64 * M];
  int j0 = blockIdx.x * 64;
  for (int t = threadIdx.x; t < 64 * M; t += 256) {
    int idx = j0 * M + t;
    float a = XaB[idx];
    for (int p = 1; p < npa; ++p) a += XaB[p * (N16 * M) + idx];
    float b = XbB[idx];
    for (int p = 1; p < npb; ++p) b += XbB[p * (N16 * M) + idx];
    sA[t] = a; sB[t] = b;
  }
  __syncthreads();
  const int t = threadIdx.x;
  for (int s = 0; s < 4; ++s) {
    int e = s * 256 + t;
    int a = e >> 5, b = e & 31;
    float sum = 0.f;
    for (int jl = 0; jl < 64; ++jl) sum += sA[jl * M + a] * sB[jl * M + b];
    Gpart[blockIdx.x * 1024 + e] = sum;
  }
}

// ------------- fused: reduce Gram + Cholesky + L^-1 + X <- X L^-T -----------
// 64 threads, grid 200 (8 rows each). Chol redone per block (cheap, parallel).
__global__ void __launch_bounds__(64)
k_apply(const float* __restrict__ Gpart, const float* __restrict__ XinB, int npin,
        float* __restrict__ Xout) {
  __shared__ float Gm[32 * 33];
  __shared__ float LI[32 * 33];  // LI[c*33+i] = Linv[i][c]
  __shared__ float Xsum[8 * M];
  const int t = threadIdx.x;
  for (int e = t; e < 1024; e += 64) {
    float s = 0.f;
    for (int b = 0; b < 25; ++b) s += Gpart[b * 1024 + e];
    Gm[(e >> 5) * 33 + (e & 31)] = s;
  }
  const int row0 = blockIdx.x * 8;
  for (int e = t; e < 8 * M; e += 64) {
    int idx = row0 * M + e;
    float v = XinB[idx];
    for (int p = 1; p < npin; ++p) v += XinB[p * (N16 * M) + idx];
    Xsum[e] = v;
  }
  __syncthreads();
  // Cholesky, lower triangle, stride 33
  for (int k = 0; k < 32; ++k) {
    if (t == 0) Gm[k * 33 + k] = sqrtf(fmaxf(Gm[k * 33 + k], 1e-30f));
    __syncthreads();
    float piv = Gm[k * 33 + k];
    if (t > k && t < 32) Gm[t * 33 + k] /= piv;
    __syncthreads();
    for (int i = k + 1; i < 32; ++i) {
      if (t < i - k) {
        int j = k + 1 + t;
        Gm[i * 33 + j] -= Gm[i * 33 + k] * Gm[j * 33 + k];
      }
    }
    __syncthreads();
  }
  // forward-substitute: lane c computes column c of L^-1
  if (t < 32) {
    int c = t;
    for (int i = c; i < 32; ++i) {
      float x = (i == c) ? 1.f : 0.f;
      for (int l = c; l < i; ++l) x -= Gm[i * 33 + l] * LI[c * 33 + l];
      LI[c * 33 + i] = x / Gm[i * 33 + i];
    }
  }
  __syncthreads();
  // Xout[r][k] = sum_{l<=k} Xsum[r][l] * Linv[k][l]; Linv[k][l] = LI[l*33+k]
  for (int e = t; e < 8 * M; e += 64) {
    int r = e >> 5, k = e & 31;
    float s = 0.f;
    for (int l = 0; l <= k; ++l) s += Xsum[r * M + l] * LI[l * 33 + k];
    Xout[(row0 + r) * M + k] = s;
  }
}

// ------------- RR eigensolve: Householder tridiag + Sturm bisection ---------
__global__ void __launch_bounds__(64)
k_rr(const float* __restrict__ Gpart, const int* __restrict__ flags,
     const int* __restrict__ Kptr, float* __restrict__ out) {
  __shared__ float Bs[32 * 33];
  __shared__ float tmp[1024];
  __shared__ float vvs[32], uus[32];
  __shared__ float dd[32], ee[32], ee2[32], evs[32];
  const int t = threadIdx.x;
  for (int e = t; e < 1024; e += 64) {
    float s = 0.f;
    for (int b = 0; b < 25; ++b) s += Gpart[b * 1024 + e];
    tmp[e] = s;
  }
  __syncthreads();
  for (int e = t; e < 1024; e += 64) {
    int i = e >> 5, j = e & 31;
    Bs[i * 33 + j] = 0.5f * (tmp[e] + tmp[j * 32 + i]);
  }
  __syncthreads();
  // Householder: steps k=0..29 produce e[k]; full symmetric trailing update
  for (int k = 0; k <= 29; ++k) {
    const int m = 31 - k;
    float xi = (t < m) ? Bs[(k + 1 + t) * 33 + k] : 0.f;
    float nx2 = wred(xi * xi);
    float x0 = Bs[(k + 1) * 33 + k];
    if (nx2 < 1e-28f) {  // uniform branch (same data all lanes)
      if (t == 0) ee[k] = x0;
      continue;
    }
    float alpha = (x0 >= 0.f) ? -sqrtf(nx2) : sqrtf(nx2);
    float h = nx2 - alpha * x0;  // = ||v||^2 / 2 > 0
    float vi = (t == 0) ? (xi - alpha) : xi;
    if (t < m) vvs[t] = vi;
    if (t == 0) ee[k] = alpha;
    __syncthreads();
    float pi = 0.f;
    if (t < m) {
      const float* rowp = &Bs[(k + 1 + t) * 33 + (k + 1)];
      for (int j = 0; j < m; ++j) pi += rowp[j] * vvs[j];
      pi /= h;
    }
    float vp = wred((t < m) ? vi * pi : 0.f);
    float Kc = vp / (2.f * h);
    float ui = pi - Kc * vi;
    if (t < m) uus[t] = ui;
    __syncthreads();
    if (t < m) {
      float* rowp = &Bs[(k + 1 + t) * 33 + (k + 1)];
      for (int j = 0; j < m; ++j) rowp[j] -= vi * uus[j] + ui * vvs[j];
    }
    __syncthreads();
  }
  if (t < 32) dd[t] = Bs[t * 33 + t];
  if (t == 0) ee[30] = Bs[31 * 33 + 30];
  if (t == 0) ee[31] = 0.f;
  __syncthreads();
  if (t < 32) ee2[t] = (t < 31) ? ee[t] * ee[t] : 0.f;
  // Gershgorin bounds
  float di = (t < 32) ? dd[t] : dd[0];
  float rr = 0.f;
  if (t < 32) {
    if (t > 0) rr += fabsf(ee[t - 1]);
    if (t < 31) rr += fabsf(ee[t]);
  }
  float lo = wredmin(di - rr) - 1e-6f;
  float hi = wredmax(di + rr) + 1e-6f;
  __syncthreads();
  // bisection: lane j finds ascending eigenvalue lambda_j
  if (t < 32) {
    float a = lo, b = hi;
    for (int it = 0; it < 40; ++it) {
      float mid = 0.5f * (a + b);
      float q = dd[0] - mid;
      int cnt = (q < 0.f) ? 1 : 0;
      for (int i = 1; i < 32; ++i) {
        float den = q;
        if (fabsf(den) < 1e-30f) den = (den < 0.f) ? -1e-30f : 1e-30f;
        q = dd[i] - mid - ee2[i - 1] / den;
        cnt += (q < 0.f) ? 1 : 0;
      }
      if (cnt <= t) a = mid; else b = mid;
    }
    evs[t] = 0.5f * (a + b);
  }
  __syncthreads();
  if (t == 0) {
    int K = Kptr ? *Kptr : 10;
    if (K < 1) K = 10;
    if (K > 32) K = 32;
    float t12 = 0.f, t13 = 0.f, t23 = 0.f;
    for (int b = 0; b < 8; ++b) {
      float f1 = flags[b * 2 + 0] ? 1.f : 0.f;
      float f2 = flags[b * 2 + 1] ? 1.f : 0.f;
      for (int k = 0; k < K; ++k) {
        float v1 = (k == 0) ? 0.f : (k == 1 ? f1 : 1.f);
        float v2 = (k == 0) ? 0.f : (k == 1 ? f2 : 1.f);
        float m3 = 2.f - 2.f * evs[31 - k];  // descending A-eigs -> Ln eigs
        t12 += (v1 - v2) * (v1 - v2);
        t13 += (v1 - m3) * (v1 - m3);
        t23 += (v2 - m3) * (v2 - m3);
      }
    }
    out[0] = 5.f * (t12 + t13 + t23) / (8.f * (float)K);
  }
}

extern "C" void kernel_launch(void* const* d_in, const int* in_sizes, int n_in,
                              void* d_out, int out_size, void* d_ws, size_t ws_size,
                              hipStream_t stream) {
  const float* feats = (const float*)d_in[0];
  const int* Kptr = (n_in > 1) ? (const int*)d_in[1] : nullptr;
  float* ws = (float*)d_ws;
  // layout (floats); RZ dead after k_prep -> GP overlays it
  float* RZ = ws;                       // 38400
  float* GP = ws;                       // 25600 (overlay)
  float* F  = ws + 38400;               // 4800
  float4* G4 = (float4*)(ws + 43200);   // 1600 float4
  float* R  = ws + 49600;               // 1600
  int* FLAGS = (int*)(ws + 51200);      // 16 ints (64 reserved)
  float* X0 = ws + 51264;               // 51200 (whole X)
  float* XA = ws + 102464;              // P*51200
  // big path needs (102464 + 2*4*51200)*4 = 2,048,256 bytes
  const int P = (ws_size >= (size_t)(102464 + 2 * NPART * 51200) * 4) ? NPART : 1;
  float* XB = XA + (size_t)P * 51200;
  const float invP = 1.f / (float)P;

  k_resize<<<dim3(7, 24), 256, 0, stream>>>(feats, RZ);
  k_prep<<<23, 256, 0, stream>>>(RZ, F, FLAGS);
  k_degree<<<100, 256, 0, stream>>>(F, R, G4, X0);

  for (int outer = 0; outer < T_OUTER; ++outer) {
    // mv1: X0 (whole) -> XA (P parts)
    k_matvec<<<dim3(200, P), 256, 0, stream>>>(F, G4, R, X0, 1, XA, P, invP);
    float* Xa = XA; float* Xb = XB;
    for (int p = 1; p < P_INNER; ++p) {
      k_matvec<<<dim3(200, P), 256, 0, stream>>>(F, G4, R, Xa, P, Xb, P, invP);
      float* t2 = Xa; Xa = Xb; Xb = t2;
    }
    // result in Xa (P parts)
    k_gram<<<25, 256, 0, stream>>>(Xa, P, Xa, P, GP);
    k_apply<<<200, 64, 0, stream>>>(GP, Xa, P, X0);
  }
  // final Rayleigh-Ritz: B = X0^T (A X0)
  k_matvec<<<dim3(200, P), 256, 0, stream>>>(F, G4, R, X0, 1, XA, P, invP);
  k_gram<<<25, 256, 0, stream>>>(X0, 1, XA, P, GP);
  k_rr<<<1, 64, 0, stream>>>(GP, FLAGS, Kptr, (float*)d_out);
}

// Round 6
// 1492.310 us; speedup vs baseline: 7.8908x; 1.0029x over previous
//
#include <hip/hip_runtime.h>
#include <hip/hip_cooperative_groups.h>
#include <math.h>

namespace cg = cooperative_groups;

#define N16 1600
#define M 32
#define T_OUTER 2
#define P_INNER 10
#define NSTEPS (2 * (P_INNER + 2) + 3)   // 27
#define BIS_IT 28
#define EPSF 1e-12f
#define XPART 51200                       // floats per partial buffer
#define LDSF 8448                         // floats of shared scratch
#define WST 68                            // padded row stride (floats), 16B-aligned

// ---------------- wave-wide butterfly reductions (64 lanes) -----------------
__device__ __forceinline__ float wred(float v) {
#pragma unroll
  for (int o = 32; o; o >>= 1) v += __shfl_xor(v, o, 64);
  return v;
}
__device__ __forceinline__ float wredmin(float v) {
#pragma unroll
  for (int o = 32; o; o >>= 1) v = fminf(v, __shfl_xor(v, o, 64));
  return v;
}
__device__ __forceinline__ float wredmax(float v) {
#pragma unroll
  for (int o = 32; o; o >>= 1) v = fmaxf(v, __shfl_xor(v, o, 64));
  return v;
}

// ---------------- resize (jax.image.resize bilinear, antialias=True) --------
__device__ inline void taps1d(int o, int* lo, int* hi, float* wsum, float w[8]) {
  int l = 4 * o - 2, h = 4 * o + 5;
  if (l < 0) l = 0;
  if (h > 159) h = 159;
  float c = 4.f * o + 1.5f, s = 0.f;
  for (int x = l; x <= h; ++x) {
    float ww = 1.f - fabsf((float)x - c) * 0.25f;
    w[x - l] = ww;
    s += ww;
  }
  *lo = l; *hi = h; *wsum = s;
}

__global__ void k_resize(const float* __restrict__ in, float* __restrict__ rz) {
  int map = blockIdx.y;
  int o = blockIdx.x * 256 + threadIdx.x;
  if (o >= N16) return;
  int oy = o / 40, ox = o % 40;
  int ly, hy, lx, hx; float sy, sx; float wy[8], wx[8];
  taps1d(oy, &ly, &hy, &sy, wy);
  taps1d(ox, &lx, &hx, &sx, wx);
  const float* src = in + (size_t)map * 160 * 160;
  float acc = 0.f;
  for (int y = ly; y <= hy; ++y) {
    float a = 0.f;
    const float* row = src + y * 160;
    for (int x = lx; x <= hx; ++x) a += wx[x - lx] * row[x];
    acc += wy[y - ly] * a;
  }
  rz[map * N16 + o] = acc / (sy * sx);
}

// ------------- prep: sign counts (lan1/lan2) + row-normalize sample0 --------
__global__ void k_prep(const float* __restrict__ rz, float* __restrict__ F,
                       int* __restrict__ flags) {
  __shared__ int sp[256], sn[256];
  int blk = blockIdx.x;
  if (blk < 16) {
    int b = blk >> 1, c = blk & 1;
    const float* m = rz + (b * 3 + c) * N16;
    int cp = 0, cn = 0;
    for (int o = threadIdx.x; o < N16; o += 256) {
      float v = m[o];
      cp += (v > 0.f);
      cn += (v < 0.f);
    }
    sp[threadIdx.x] = cp; sn[threadIdx.x] = cn;
    __syncthreads();
    for (int s = 128; s > 0; s >>= 1) {
      if (threadIdx.x < s) {
        sp[threadIdx.x] += sp[threadIdx.x + s];
        sn[threadIdx.x] += sn[threadIdx.x + s];
      }
      __syncthreads();
    }
    if (threadIdx.x == 0) flags[blk] = (sp[0] == 0 || sn[0] == 0) ? 1 : 0;
  } else {
    int n = (blk - 16) * 256 + threadIdx.x;
    if (n < N16) {
      float x = rz[n], y = rz[N16 + n], z = rz[2 * N16 + n];
      float nrm = sqrtf(x * x + y * y + z * z);
      float s = 1.f / fmaxf(nrm, EPSF);
      F[n * 3 + 0] = x * s; F[n * 3 + 1] = y * s; F[n * 3 + 2] = z * s;
    }
  }
}

// ------------- degree + G4 + X0 init (fused) --------------------------------
__global__ void k_degree(const float* __restrict__ F, float* __restrict__ R,
                         float4* __restrict__ G4, float* __restrict__ X0) {
  __shared__ float Fl[4800];
  __shared__ float red[256];
  for (int t = threadIdx.x; t < 4800; t += 256) Fl[t] = F[t];
  __syncthreads();
  int rl = threadIdx.x >> 4, jt = threadIdx.x & 15;
  int i = blockIdx.x * 16 + rl;
  float fx = Fl[i * 3], fy = Fl[i * 3 + 1], fz = Fl[i * 3 + 2];
  float s = 0.f;
  for (int j = jt; j < N16; j += 16) {
    float w = fx * Fl[j * 3] + fy * Fl[j * 3 + 1] + fz * Fl[j * 3 + 2];
    if (w > 0.f) s += w;
  }
  red[threadIdx.x] = s;
  __syncthreads();
  for (int st = 8; st > 0; st >>= 1) {
    if (jt < st) red[threadIdx.x] += red[threadIdx.x + st];
    __syncthreads();
  }
  if (jt == 0) {
    float d = red[threadIdx.x];
    if (d < EPSF) d = 1.f;
    float r = rsqrtf(d);
    R[i] = r;
    float4 g; g.x = r * fx; g.y = r * fy; g.z = r * fz; g.w = 0.f;
    G4[i] = g;
  }
  for (int e = threadIdx.x; e < 512; e += 256) {
    int n = blockIdx.x * 16 + (e >> 5);
    int k = e & 31;
    unsigned u = ((unsigned)n * 2654435761u) ^ ((unsigned)k * 0x9E3779B9u);
    u = u * 1664525u + 1013904223u;
    u ^= u >> 16; u *= 2246822519u; u ^= u >> 13;
    X0[n * M + k] = ((float)(u >> 8) * (1.f / 8388608.f)) - 1.f;
  }
}

// ============== phase device functions (shared by coop + fallback) ==========

// Xout_part[jp] = 0.5*([jp==0]*Xin + S_jp Xin). Register tile 4j x 4k x 4r.
__device__ void mv_phase(const float* __restrict__ F, const float4* __restrict__ G4,
                         const float* __restrict__ R, const float* __restrict__ Xin,
                         int npin, float* __restrict__ Xout, int rb, int jp, int P,
                         float* LDSu, int t) {
  float* XsT = LDSu;          // [32][WST]  X transposed: XsT[k*WST + j]
  float* Ws  = LDSu + 2176;   // [32][WST]  w:           Ws[i*WST + j]
  float* Red = LDSu + 4352;   // [4][1024]
  const int rg = t & 7, kg = (t >> 3) & 7, jg = t >> 6;
  const int i0 = rb * 32;
  const int JP = N16 / P;
  const int jlo = jp * JP;
  const int NCH = JP / 64;
  const int il = t & 31;
  const float fx = F[(i0 + il) * 3], fy = F[(i0 + il) * 3 + 1],
              fz = F[(i0 + il) * 3 + 2];
  float acc[4][4];
#pragma unroll
  for (int r = 0; r < 4; ++r)
#pragma unroll
    for (int kk = 0; kk < 4; ++kk) acc[r][kk] = 0.f;

  for (int c = 0; c < NCH; ++c) {
    const int jbase = jlo + c * 64;
    __syncthreads();
    // stage XsT (transposed, partials summed)
#pragma unroll
    for (int it = 0; it < 2; ++it) {
      int e = it * 256 + t;            // 0..511
      int jl = e >> 3, kq = e & 7;
      const float4* p0 = (const float4*)Xin + (size_t)(jbase + jl) * 8 + kq;
      float4 v = p0[0];
      for (int p = 1; p < npin; ++p) {
        float4 a = p0[(size_t)p * (XPART / 4)];
        v.x += a.x; v.y += a.y; v.z += a.z; v.w += a.w;
      }
      XsT[(kq * 4 + 0) * WST + jl] = v.x;
      XsT[(kq * 4 + 1) * WST + jl] = v.y;
      XsT[(kq * 4 + 2) * WST + jl] = v.z;
      XsT[(kq * 4 + 3) * WST + jl] = v.w;
    }
    // stage Ws: w[il][jl], jl = it*8 + (t>>5)
#pragma unroll
    for (int it = 0; it < 8; ++it) {
      int jl = it * 8 + (t >> 5);
      float4 g = G4[jbase + jl];
      Ws[il * WST + jl] = fmaxf(fx * g.x + fy * g.y + fz * g.z, 0.f);
    }
    __syncthreads();
    // MAC: this wave's 4 quads; rows rg+8r, cols kg+8kk (bank-spread by 1)
#pragma unroll
    for (int q = 0; q < 4; ++q) {
      const int jq = (jg * 4 + q) * 4;
      float4 wv[4], xv[4];
#pragma unroll
      for (int r = 0; r < 4; ++r)
        wv[r] = *(const float4*)&Ws[(rg + 8 * r) * WST + jq];
#pragma unroll
      for (int kk = 0; kk < 4; ++kk)
        xv[kk] = *(const float4*)&XsT[(kg + 8 * kk) * WST + jq];
#pragma unroll
      for (int r = 0; r < 4; ++r)
#pragma unroll
        for (int kk = 0; kk < 4; ++kk)
          acc[r][kk] += wv[r].x * xv[kk].x + wv[r].y * xv[kk].y +
                        wv[r].z * xv[kk].z + wv[r].w * xv[kk].w;
    }
  }
  __syncthreads();
#pragma unroll
  for (int r = 0; r < 4; ++r)
#pragma unroll
    for (int kk = 0; kk < 4; ++kk)
      Red[jg * 1024 + (rg + 8 * r) * 32 + (kg + 8 * kk)] = acc[r][kk];
  __syncthreads();
#pragma unroll
  for (int it = 0; it < 4; ++it) {
    int o = it * 256 + t;              // 0..1023
    int ilw = o >> 5, k = o & 31;
    float s = Red[o] + Red[1024 + o] + Red[2048 + o] + Red[3072 + o];
    int gi = i0 + ilw;
    float xik = 0.f;
    if (jp == 0)
      for (int p = 0; p < npin; ++p) xik += Xin[(size_t)p * XPART + gi * 32 + k];
    Xout[(size_t)jp * XPART + gi * 32 + k] = 0.5f * (xik + R[gi] * s);
  }
}

__device__ void gram_phase(const float* __restrict__ Xa, int npa,
                           const float* __restrict__ Xb, int npb,
                           float* __restrict__ Gpart, float* LDSu, int bx, int t) {
  float* sA = LDSu;           // 2048
  float* sB = LDSu + 2048;    // 2048
  int j0 = bx * 64;
  for (int s = t; s < 64 * M; s += 256) {
    int idx = j0 * M + s;
    float a = Xa[idx];
    for (int p = 1; p < npa; ++p) a += Xa[(size_t)p * XPART + idx];
    float b = Xb[idx];
    for (int p = 1; p < npb; ++p) b += Xb[(size_t)p * XPART + idx];
    sA[s] = a; sB[s] = b;
  }
  __syncthreads();
  for (int s = 0; s < 4; ++s) {
    int e = s * 256 + t;
    int a = e >> 5, b = e & 31;
    float sum = 0.f;
    for (int jl = 0; jl < 64; ++jl) sum += sA[jl * M + a] * sB[jl * M + b];
    Gpart[bx * 1024 + e] = sum;
  }
}

// reduce Gram + Cholesky + L^-1 + X0 <- Xsum * L^-T   (8 rows per block)
__device__ void apply_phase(const float* __restrict__ Gpart,
                            const float* __restrict__ XinB, int npin,
                            float* __restrict__ Xout, float* LDSu, int bx, int t) {
  float* Gm = LDSu;            // 32*33
  float* LI = LDSu + 1056;     // 32*33 : LI[c*33+i] = Linv[i][c]
  float* Xsum = LDSu + 2112;   // 256
  for (int e = t; e < 1024; e += 256) {
    float s = 0.f;
    for (int b = 0; b < 25; ++b) s += Gpart[b * 1024 + e];
    Gm[(e >> 5) * 33 + (e & 31)] = s;
  }
  const int row0 = bx * 8;
  {
    int idx = row0 * M + t;
    float v = XinB[idx];
    for (int p = 1; p < npin; ++p) v += XinB[(size_t)p * XPART + idx];
    Xsum[t] = v;
  }
  __syncthreads();
  for (int k = 0; k < 32; ++k) {
    if (t == 0) Gm[k * 33 + k] = sqrtf(fmaxf(Gm[k * 33 + k], 1e-30f));
    __syncthreads();
    float piv = Gm[k * 33 + k];
    if (t > k && t < 32) Gm[t * 33 + k] /= piv;
    __syncthreads();
    for (int e = t; e < 1024; e += 256) {
      int i = e >> 5, j = e & 31;
      if (i > k && j > k && j <= i) Gm[i * 33 + j] -= Gm[i * 33 + k] * Gm[j * 33 + k];
    }
    __syncthreads();
  }
  if (t < 32) {
    int c = t;
    for (int i = c; i < 32; ++i) {
      float x = (i == c) ? 1.f : 0.f;
      for (int l = c; l < i; ++l) x -= Gm[i * 33 + l] * LI[c * 33 + l];
      LI[c * 33 + i] = x / Gm[i * 33 + i];
    }
  }
  __syncthreads();
  {
    int r = t >> 5, k = t & 31;
    float s = 0.f;
    for (int l = 0; l <= k; ++l) s += Xsum[r * M + l] * LI[l * 33 + k];
    Xout[(row0 + r) * M + k] = s;
  }
}

// Householder tridiag + Sturm bisection + final loss
__device__ void rr_phase(const float* __restrict__ Gpart,
                         const int* __restrict__ flags,
                         const int* __restrict__ Kptr,
                         float* __restrict__ out, float* Ph, int t) {
  float* Bs   = Ph;           // 1056
  float* part = Ph + 1056;    // 1024
  float* vvs  = Ph + 2080;
  float* uus  = Ph + 2112;
  float* dd   = Ph + 2144;
  float* ee   = Ph + 2176;
  float* ee2  = Ph + 2208;
  float* evs  = Ph + 2240;
  float* shs  = Ph + 2272;
  for (int e = t; e < 1024; e += 256) {
    float s = 0.f;
    for (int b = 0; b < 25; ++b) s += Gpart[b * 1024 + e];
    part[e] = s;
  }
  __syncthreads();
  for (int e = t; e < 1024; e += 256) {
    int i = e >> 5, j = e & 31;
    Bs[i * 33 + j] = 0.5f * (part[e] + part[j * 32 + i]);
  }
  __syncthreads();
  for (int k = 0; k <= 29; ++k) {
    const int m = 31 - k;
    if (t < 64) {
      float xi = (t < m) ? Bs[(k + 1 + t) * 33 + k] : 0.f;
      float nx2 = wred(xi * xi);
      if (t == 0) { shs[0] = nx2; shs[1] = Bs[(k + 1) * 33 + k]; }
    }
    __syncthreads();
    float nx2 = shs[0], x0 = shs[1];
    if (nx2 < 1e-28f) {
      if (t == 0) ee[k] = x0;
      __syncthreads();
      continue;
    }
    if (t < 32) {
      float alpha = (x0 >= 0.f) ? -sqrtf(nx2) : sqrtf(nx2);
      float h = nx2 - alpha * x0;
      float xi = (t < m) ? Bs[(k + 1 + t) * 33 + k] : 0.f;
      float vi = (t == 0) ? (xi - alpha) : xi;
      vvs[t] = (t < m) ? vi : 0.f;
      if (t == 0) { ee[k] = alpha; shs[2] = h; }
    }
    __syncthreads();
    {
      int i = t >> 3, s = t & 7;
      float p = 0.f;
      if (i < m) {
        const float* rowp = &Bs[(k + 1 + i) * 33 + (k + 1)];
        for (int j = s; j < m; j += 8) p += rowp[j] * vvs[j];
      }
      part[t] = p;
    }
    __syncthreads();
    if (t < 64) {
      float h = shs[2];
      float pi = 0.f;
      if (t < 32) {
#pragma unroll
        for (int s = 0; s < 8; ++s) pi += part[t * 8 + s];
        pi /= h;
      }
      float vip = (t < 32) ? vvs[t] * pi : 0.f;
      float vp = wred(vip);
      float Kc = vp / (2.f * h);
      if (t < 32) uus[t] = (t < m) ? (pi - Kc * vvs[t]) : 0.f;
    }
    __syncthreads();
    for (int e = t; e < 1024; e += 256) {
      int i = e >> 5, j = e & 31;
      if (i < m && j < m)
        Bs[(k + 1 + i) * 33 + (k + 1 + j)] -= vvs[i] * uus[j] + uus[i] * vvs[j];
    }
    __syncthreads();
  }
  if (t < 32) dd[t] = Bs[t * 33 + t];
  if (t == 0) { ee[30] = Bs[31 * 33 + 30]; ee[31] = 0.f; }
  __syncthreads();
  if (t < 32) ee2[t] = (t < 31) ? ee[t] * ee[t] : 0.f;
  __syncthreads();
  if (t < 64) {
    int tt = t & 31;
    float di = dd[tt];
    float r = 0.f;
    if (tt > 0) r += fabsf(ee[tt - 1]);
    if (tt < 31) r += fabsf(ee[tt]);
    float lo = wredmin(di - r);
    float hi = wredmax(di + r);
    if (t == 0) { shs[0] = lo - 1e-6f; shs[1] = hi + 1e-6f; }
  }
  __syncthreads();
  if (t < 32) {
    float a = shs[0], b = shs[1];
    for (int it = 0; it < BIS_IT; ++it) {
      float mid = 0.5f * (a + b);
      float q = dd[0] - mid;
      int cnt = (q < 0.f) ? 1 : 0;
#pragma unroll
      for (int i = 1; i < 32; ++i) {
        float den = q;
        float ad = fabsf(den);
        den = (ad < 1e-30f) ? ((den < 0.f) ? -1e-30f : 1e-30f) : den;
        q = dd[i] - mid - ee2[i - 1] * __builtin_amdgcn_rcpf(den);
        cnt += (q < 0.f) ? 1 : 0;
      }
      if (cnt <= t) a = mid; else b = mid;
    }
    evs[t] = 0.5f * (a + b);
  }
  __syncthreads();
  if (t == 0) {
    int K = Kptr ? *Kptr : 10;
    if (K < 1) K = 10;
    if (K > 32) K = 32;
    float t12 = 0.f, t13 = 0.f, t23 = 0.f;
    for (int b = 0; b < 8; ++b) {
      float f1 = flags[b * 2 + 0] ? 1.f : 0.f;
      float f2 = flags[b * 2 + 1] ? 1.f : 0.f;
      for (int k = 0; k < K; ++k) {
        float v1 = (k == 0) ? 0.f : (k == 1 ? f1 : 1.f);
        float v2 = (k == 0) ? 0.f : (k == 1 ? f2 : 1.f);
        float m3 = 2.f - 2.f * evs[31 - k];
        t12 += (v1 - v2) * (v1 - v2);
        t13 += (v1 - m3) * (v1 - m3);
        t23 += (v2 - m3) * (v2 - m3);
      }
    }
    out[0] = 5.f * (t12 + t13 + t23) / (8.f * (float)K);
  }
}

// ------------- unified step dispatcher (identical in coop & fallback) -------
__device__ void do_step(int s, const float* F, const float4* G4, const float* R,
                        float* X0, float* XA, float* XB, float* GP,
                        const int* flags, const int* Kptr, float* out, int P,
                        float* LDSu, int bx, int t) {
  const int per = P_INNER + 2;
  float* FIN = (P_INNER & 1) ? XA : XB;  // buffer holding last inner-MV result
  if (s < 2 * per) {
    int ls = s % per;
    if (ls < P_INNER) {
      if (bx < 50 * P) {
        int rb = bx / P, jp = bx % P;
        const float* Xin; float* Xout; int npin;
        if (ls == 0)      { Xin = X0; npin = 1; Xout = XA; }
        else if (ls & 1)  { Xin = XA; npin = P; Xout = XB; }
        else              { Xin = XB; npin = P; Xout = XA; }
        mv_phase(F, G4, R, Xin, npin, Xout, rb, jp, P, LDSu, t);
      }
    } else if (ls == P_INNER) {
      if (bx < 25) gram_phase(FIN, P, FIN, P, GP, LDSu, bx, t);
    } else {
      if (bx < 200) apply_phase(GP, FIN, P, X0, LDSu, bx, t);
    }
  } else {
    int ls = s - 2 * per;
    if (ls == 0) {
      if (bx < 50 * P) {
        int rb = bx / P, jp = bx % P;
        mv_phase(F, G4, R, X0, 1, XA, rb, jp, P, LDSu, t);
      }
    } else if (ls == 1) {
      if (bx < 25) gram_phase(X0, 1, XA, P, GP, LDSu, bx, t);
    } else {
      if (bx == 0) rr_phase(GP, flags, Kptr, out, LDSu, t);
    }
  }
}

__global__ void __launch_bounds__(256)
k_solve(const float* F, const float4* G4, const float* R, float* X0,
        float* XA, float* XB, float* GP, const int* flags, const int* Kptr,
        float* out, int P) {
  cg::grid_group grid = cg::this_grid();
  __shared__ __align__(16) float LDSu[LDSF];
  const int bx = blockIdx.x, t = threadIdx.x;
  for (int s = 0; s < NSTEPS; ++s) {
    do_step(s, F, G4, R, X0, XA, XB, GP, flags, Kptr, out, P, LDSu, bx, t);
    if (s + 1 < NSTEPS) grid.sync();
  }
}

__global__ void __launch_bounds__(256)
k_step(int s, const float* F, const float4* G4, const float* R, float* X0,
       float* XA, float* XB, float* GP, const int* flags, const int* Kptr,
       float* out, int P) {
  __shared__ __align__(16) float LDSu[LDSF];
  do_step(s, F, G4, R, X0, XA, XB, GP, flags, Kptr, out, P, LDSu,
          blockIdx.x, threadIdx.x);
}

extern "C" void kernel_launch(void* const* d_in, const int* in_sizes, int n_in,
                              void* d_out, int out_size, void* d_ws, size_t ws_size,
                              hipStream_t stream) {
  const float* feats = (const float*)d_in[0];
  const int* Kptr = (n_in > 1) ? (const int*)d_in[1] : nullptr;
  float* ws = (float*)d_ws;
  float* RZ = ws;                       // 38400 (dead after k_prep)
  float* GP = ws;                       // 25600 (overlay)
  float* Fb = ws + 38400;               // 4800
  float4* G4 = (float4*)(ws + 43200);   // 1600 float4
  float* Rb = ws + 49600;               // 1600
  int* FLAGS = (int*)(ws + 51200);      // 16 ints (64 reserved)
  float* X0 = ws + 51264;               // 51200
  float* XA = ws + 102464;              // P*51200
  const int P = (ws_size >= (size_t)(102464 + 2 * 5 * XPART) * 4) ? 5 : 1;
  float* XB = XA + (size_t)P * XPART;

  k_resize<<<dim3(7, 24), 256, 0, stream>>>(feats, RZ);
  k_prep<<<23, 256, 0, stream>>>(RZ, Fb, FLAGS);
  k_degree<<<100, 256, 0, stream>>>(Fb, Rb, G4, X0);

  const float* Fc = Fb;
  const float4* Gc = G4;
  const float* Rc = Rb;
  const int* FLc = FLAGS;
  float* outp = (float*)d_out;
  int Pv = P;
  void* args[] = {(void*)&Fc, (void*)&Gc, (void*)&Rc, (void*)&X0, (void*)&XA,
                  (void*)&XB, (void*)&GP, (void*)&FLc, (void*)&Kptr,
                  (void*)&outp, (void*)&Pv};
  hipError_t err = hipLaunchCooperativeKernel(
      (const void*)k_solve, dim3(50 * P, 1, 1), dim3(256, 1, 1), args, 0, stream);
  if (err != hipSuccess) {
    // fallback: identical phase sequence as separate launches
    for (int s = 0; s < NSTEPS; ++s)
      k_step<<<dim3(50 * P), 256, 0, stream>>>(s, Fc, Gc, Rc, X0, XA, XB, GP,
                                               FLc, Kptr, outp, Pv);
  }
}

// Round 7
// 1012.854 us; speedup vs baseline: 11.6261x; 1.4734x over previous
//
#include <hip/hip_runtime.h>
#include <math.h>

#define N16 1600
#define M 32
#define T_OUTER 2
#define P_INNER 10
#define NSTEPS (2 * (P_INNER + 2) + 3)   // 27
#define BIS_IT 28
#define EPSF 1e-12f
#define XPART 51200                       // floats per partial buffer
#define LDSF 8448                         // floats of shared scratch
#define WST 68                            // padded row stride (floats), 16B-aligned

// ---------------- wave-wide butterfly reductions (64 lanes) -----------------
__device__ __forceinline__ float wred(float v) {
#pragma unroll
  for (int o = 32; o; o >>= 1) v += __shfl_xor(v, o, 64);
  return v;
}
__device__ __forceinline__ float wredmin(float v) {
#pragma unroll
  for (int o = 32; o; o >>= 1) v = fminf(v, __shfl_xor(v, o, 64));
  return v;
}
__device__ __forceinline__ float wredmax(float v) {
#pragma unroll
  for (int o = 32; o; o >>= 1) v = fmaxf(v, __shfl_xor(v, o, 64));
  return v;
}

// ---------------- custom grid barrier (sense-reversing, agent scope) --------
// cnt and gen live in device ws, 128 B apart. Init'ed by k_degree with
// agent-scope atomic stores (plain stores could sit dirty in one XCD's L2).
__device__ __forceinline__ void grid_barrier(unsigned* cnt, unsigned* gen,
                                             unsigned nb, int t) {
  __syncthreads();  // all block's mem ops issued & waited (vmcnt drain)
  if (t == 0) {
    unsigned g = __hip_atomic_load(gen, __ATOMIC_RELAXED, __HIP_MEMORY_SCOPE_AGENT);
    unsigned a = __hip_atomic_fetch_add(cnt, 1u, __ATOMIC_ACQ_REL,
                                        __HIP_MEMORY_SCOPE_AGENT);
    if (a + 1u == nb) {
      __hip_atomic_store(cnt, 0u, __ATOMIC_RELAXED, __HIP_MEMORY_SCOPE_AGENT);
      __hip_atomic_store(gen, g + 1u, __ATOMIC_RELEASE, __HIP_MEMORY_SCOPE_AGENT);
    } else {
      while (__hip_atomic_load(gen, __ATOMIC_RELAXED,
                               __HIP_MEMORY_SCOPE_AGENT) == g)
        __builtin_amdgcn_s_sleep(2);
      (void)__hip_atomic_load(gen, __ATOMIC_ACQUIRE, __HIP_MEMORY_SCOPE_AGENT);
    }
  }
  __syncthreads();
}

// ---------------- resize (jax.image.resize bilinear, antialias=True) --------
__device__ inline void taps1d(int o, int* lo, int* hi, float* wsum, float w[8]) {
  int l = 4 * o - 2, h = 4 * o + 5;
  if (l < 0) l = 0;
  if (h > 159) h = 159;
  float c = 4.f * o + 1.5f, s = 0.f;
  for (int x = l; x <= h; ++x) {
    float ww = 1.f - fabsf((float)x - c) * 0.25f;
    w[x - l] = ww;
    s += ww;
  }
  *lo = l; *hi = h; *wsum = s;
}

__global__ void k_resize(const float* __restrict__ in, float* __restrict__ rz) {
  int map = blockIdx.y;
  int o = blockIdx.x * 256 + threadIdx.x;
  if (o >= N16) return;
  int oy = o / 40, ox = o % 40;
  int ly, hy, lx, hx; float sy, sx; float wy[8], wx[8];
  taps1d(oy, &ly, &hy, &sy, wy);
  taps1d(ox, &lx, &hx, &sx, wx);
  const float* src = in + (size_t)map * 160 * 160;
  float acc = 0.f;
  for (int y = ly; y <= hy; ++y) {
    float a = 0.f;
    const float* row = src + y * 160;
    for (int x = lx; x <= hx; ++x) a += wx[x - lx] * row[x];
    acc += wy[y - ly] * a;
  }
  rz[map * N16 + o] = acc / (sy * sx);
}

// ------------- prep: sign counts (lan1/lan2) + row-normalize sample0 --------
__global__ void k_prep(const float* __restrict__ rz, float* __restrict__ F,
                       int* __restrict__ flags) {
  __shared__ int sp[256], sn[256];
  int blk = blockIdx.x;
  if (blk < 16) {
    int b = blk >> 1, c = blk & 1;
    const float* m = rz + (b * 3 + c) * N16;
    int cp = 0, cn = 0;
    for (int o = threadIdx.x; o < N16; o += 256) {
      float v = m[o];
      cp += (v > 0.f);
      cn += (v < 0.f);
    }
    sp[threadIdx.x] = cp; sn[threadIdx.x] = cn;
    __syncthreads();
    for (int s = 128; s > 0; s >>= 1) {
      if (threadIdx.x < s) {
        sp[threadIdx.x] += sp[threadIdx.x + s];
        sn[threadIdx.x] += sn[threadIdx.x + s];
      }
      __syncthreads();
    }
    if (threadIdx.x == 0) flags[blk] = (sp[0] == 0 || sn[0] == 0) ? 1 : 0;
  } else {
    int n = (blk - 16) * 256 + threadIdx.x;
    if (n < N16) {
      float x = rz[n], y = rz[N16 + n], z = rz[2 * N16 + n];
      float nrm = sqrtf(x * x + y * y + z * z);
      float s = 1.f / fmaxf(nrm, EPSF);
      F[n * 3 + 0] = x * s; F[n * 3 + 1] = y * s; F[n * 3 + 2] = z * s;
    }
  }
}

// ------------- degree + G4 + X0 init + barrier init (fused) -----------------
__global__ void k_degree(const float* __restrict__ F, float* __restrict__ R,
                         float4* __restrict__ G4, float* __restrict__ X0,
                         unsigned* __restrict__ bcnt, unsigned* __restrict__ bgen) {
  if (blockIdx.x == 0 && threadIdx.x == 0) {
    __hip_atomic_store(bcnt, 0u, __ATOMIC_RELEASE, __HIP_MEMORY_SCOPE_AGENT);
    __hip_atomic_store(bgen, 0u, __ATOMIC_RELEASE, __HIP_MEMORY_SCOPE_AGENT);
  }
  __shared__ float Fl[4800];
  __shared__ float red[256];
  for (int t = threadIdx.x; t < 4800; t += 256) Fl[t] = F[t];
  __syncthreads();
  int rl = threadIdx.x >> 4, jt = threadIdx.x & 15;
  int i = blockIdx.x * 16 + rl;
  float fx = Fl[i * 3], fy = Fl[i * 3 + 1], fz = Fl[i * 3 + 2];
  float s = 0.f;
  for (int j = jt; j < N16; j += 16) {
    float w = fx * Fl[j * 3] + fy * Fl[j * 3 + 1] + fz * Fl[j * 3 + 2];
    if (w > 0.f) s += w;
  }
  red[threadIdx.x] = s;
  __syncthreads();
  for (int st = 8; st > 0; st >>= 1) {
    if (jt < st) red[threadIdx.x] += red[threadIdx.x + st];
    __syncthreads();
  }
  if (jt == 0) {
    float d = red[threadIdx.x];
    if (d < EPSF) d = 1.f;
    float r = rsqrtf(d);
    R[i] = r;
    float4 g; g.x = r * fx; g.y = r * fy; g.z = r * fz; g.w = 0.f;
    G4[i] = g;
  }
  for (int e = threadIdx.x; e < 512; e += 256) {
    int n = blockIdx.x * 16 + (e >> 5);
    int k = e & 31;
    unsigned u = ((unsigned)n * 2654435761u) ^ ((unsigned)k * 0x9E3779B9u);
    u = u * 1664525u + 1013904223u;
    u ^= u >> 16; u *= 2246822519u; u ^= u >> 13;
    X0[n * M + k] = ((float)(u >> 8) * (1.f / 8388608.f)) - 1.f;
  }
}

// ============== phase device functions (shared by coop + fallback) ==========

// Xout_part[jp] = 0.5*([jp==0]*Xin + S_jp Xin). Register tile 4j x 4k x 4r.
__device__ void mv_phase(const float* __restrict__ F, const float4* __restrict__ G4,
                         const float* __restrict__ R, const float* __restrict__ Xin,
                         int npin, float* __restrict__ Xout, int rb, int jp, int P,
                         float* LDSu, int t) {
  float* XsT = LDSu;          // [32][WST]  X transposed: XsT[k*WST + j]
  float* Ws  = LDSu + 2176;   // [32][WST]  w:           Ws[i*WST + j]
  float* Red = LDSu + 4352;   // [4][1024]
  const int rg = t & 7, kg = (t >> 3) & 7, jg = t >> 6;
  const int i0 = rb * 32;
  const int JP = N16 / P;
  const int jlo = jp * JP;
  const int NCH = JP / 64;
  const int il = t & 31;
  const float fx = F[(i0 + il) * 3], fy = F[(i0 + il) * 3 + 1],
              fz = F[(i0 + il) * 3 + 2];
  float acc[4][4];
#pragma unroll
  for (int r = 0; r < 4; ++r)
#pragma unroll
    for (int kk = 0; kk < 4; ++kk) acc[r][kk] = 0.f;

  for (int c = 0; c < NCH; ++c) {
    const int jbase = jlo + c * 64;
    __syncthreads();
    // stage XsT (transposed, partials summed)
#pragma unroll
    for (int it = 0; it < 2; ++it) {
      int e = it * 256 + t;            // 0..511
      int jl = e >> 3, kq = e & 7;
      const float4* p0 = (const float4*)Xin + (size_t)(jbase + jl) * 8 + kq;
      float4 v = p0[0];
      for (int p = 1; p < npin; ++p) {
        float4 a = p0[(size_t)p * (XPART / 4)];
        v.x += a.x; v.y += a.y; v.z += a.z; v.w += a.w;
      }
      XsT[(kq * 4 + 0) * WST + jl] = v.x;
      XsT[(kq * 4 + 1) * WST + jl] = v.y;
      XsT[(kq * 4 + 2) * WST + jl] = v.z;
      XsT[(kq * 4 + 3) * WST + jl] = v.w;
    }
    // stage Ws: w[il][jl], jl = it*8 + (t>>5)
#pragma unroll
    for (int it = 0; it < 8; ++it) {
      int jl = it * 8 + (t >> 5);
      float4 g = G4[jbase + jl];
      Ws[il * WST + jl] = fmaxf(fx * g.x + fy * g.y + fz * g.z, 0.f);
    }
    __syncthreads();
    // MAC: this wave's 4 quads; rows rg+8r, cols kg+8kk
#pragma unroll
    for (int q = 0; q < 4; ++q) {
      const int jq = (jg * 4 + q) * 4;
      float4 wv[4], xv[4];
#pragma unroll
      for (int r = 0; r < 4; ++r)
        wv[r] = *(const float4*)&Ws[(rg + 8 * r) * WST + jq];
#pragma unroll
      for (int kk = 0; kk < 4; ++kk)
        xv[kk] = *(const float4*)&XsT[(kg + 8 * kk) * WST + jq];
#pragma unroll
      for (int r = 0; r < 4; ++r)
#pragma unroll
        for (int kk = 0; kk < 4; ++kk)
          acc[r][kk] += wv[r].x * xv[kk].x + wv[r].y * xv[kk].y +
                        wv[r].z * xv[kk].z + wv[r].w * xv[kk].w;
    }
  }
  __syncthreads();
#pragma unroll
  for (int r = 0; r < 4; ++r)
#pragma unroll
    for (int kk = 0; kk < 4; ++kk)
      Red[jg * 1024 + (rg + 8 * r) * 32 + (kg + 8 * kk)] = acc[r][kk];
  __syncthreads();
#pragma unroll
  for (int it = 0; it < 4; ++it) {
    int o = it * 256 + t;              // 0..1023
    int ilw = o >> 5, k = o & 31;
    float s = Red[o] + Red[1024 + o] + Red[2048 + o] + Red[3072 + o];
    int gi = i0 + ilw;
    float xik = 0.f;
    if (jp == 0)
      for (int p = 0; p < npin; ++p) xik += Xin[(size_t)p * XPART + gi * 32 + k];
    Xout[(size_t)jp * XPART + gi * 32 + k] = 0.5f * (xik + R[gi] * s);
  }
}

__device__ void gram_phase(const float* __restrict__ Xa, int npa,
                           const float* __restrict__ Xb, int npb,
                           float* __restrict__ Gpart, float* LDSu, int bx, int t) {
  float* sA = LDSu;           // 2048
  float* sB = LDSu + 2048;    // 2048
  int j0 = bx * 64;
  for (int s = t; s < 64 * M; s += 256) {
    int idx = j0 * M + s;
    float a = Xa[idx];
    for (int p = 1; p < npa; ++p) a += Xa[(size_t)p * XPART + idx];
    float b = Xb[idx];
    for (int p = 1; p < npb; ++p) b += Xb[(size_t)p * XPART + idx];
    sA[s] = a; sB[s] = b;
  }
  __syncthreads();
  for (int s = 0; s < 4; ++s) {
    int e = s * 256 + t;
    int a = e >> 5, b = e & 31;
    float sum = 0.f;
    for (int jl = 0; jl < 64; ++jl) sum += sA[jl * M + a] * sB[jl * M + b];
    Gpart[bx * 1024 + e] = sum;
  }
}

// reduce Gram + Cholesky + L^-1 + X0 <- Xsum * L^-T   (8 rows per block)
__device__ void apply_phase(const float* __restrict__ Gpart,
                            const float* __restrict__ XinB, int npin,
                            float* __restrict__ Xout, float* LDSu, int bx, int t) {
  float* Gm = LDSu;            // 32*33
  float* LI = LDSu + 1056;     // 32*33 : LI[c*33+i] = Linv[i][c]
  float* Xsum = LDSu + 2112;   // 256
  for (int e = t; e < 1024; e += 256) {
    float s = 0.f;
    for (int b = 0; b < 25; ++b) s += Gpart[b * 1024 + e];
    Gm[(e >> 5) * 33 + (e & 31)] = s;
  }
  const int row0 = bx * 8;
  {
    int idx = row0 * M + t;
    float v = XinB[idx];
    for (int p = 1; p < npin; ++p) v += XinB[(size_t)p * XPART + idx];
    Xsum[t] = v;
  }
  __syncthreads();
  for (int k = 0; k < 32; ++k) {
    if (t == 0) Gm[k * 33 + k] = sqrtf(fmaxf(Gm[k * 33 + k], 1e-30f));
    __syncthreads();
    float piv = Gm[k * 33 + k];
    if (t > k && t < 32) Gm[t * 33 + k] /= piv;
    __syncthreads();
    for (int e = t; e < 1024; e += 256) {
      int i = e >> 5, j = e & 31;
      if (i > k && j > k && j <= i) Gm[i * 33 + j] -= Gm[i * 33 + k] * Gm[j * 33 + k];
    }
    __syncthreads();
  }
  if (t < 32) {
    int c = t;
    for (int i = c; i < 32; ++i) {
      float x = (i == c) ? 1.f : 0.f;
      for (int l = c; l < i; ++l) x -= Gm[i * 33 + l] * LI[c * 33 + l];
      LI[c * 33 + i] = x / Gm[i * 33 + i];
    }
  }
  __syncthreads();
  {
    int r = t >> 5, k = t & 31;
    float s = 0.f;
    for (int l = 0; l <= k; ++l) s += Xsum[r * M + l] * LI[l * 33 + k];
    Xout[(row0 + r) * M + k] = s;
  }
}

// Householder tridiag + Sturm bisection + final loss
__device__ void rr_phase(const float* __restrict__ Gpart,
                         const int* __restrict__ flags,
                         const int* __restrict__ Kptr,
                         float* __restrict__ out, float* Ph, int t) {
  float* Bs   = Ph;           // 1056
  float* part = Ph + 1056;    // 1024
  float* vvs  = Ph + 2080;
  float* uus  = Ph + 2112;
  float* dd   = Ph + 2144;
  float* ee   = Ph + 2176;
  float* ee2  = Ph + 2208;
  float* evs  = Ph + 2240;
  float* shs  = Ph + 2272;
  for (int e = t; e < 1024; e += 256) {
    float s = 0.f;
    for (int b = 0; b < 25; ++b) s += Gpart[b * 1024 + e];
    part[e] = s;
  }
  __syncthreads();
  for (int e = t; e < 1024; e += 256) {
    int i = e >> 5, j = e & 31;
    Bs[i * 33 + j] = 0.5f * (part[e] + part[j * 32 + i]);
  }
  __syncthreads();
  for (int k = 0; k <= 29; ++k) {
    const int m = 31 - k;
    if (t < 64) {
      float xi = (t < m) ? Bs[(k + 1 + t) * 33 + k] : 0.f;
      float nx2 = wred(xi * xi);
      if (t == 0) { shs[0] = nx2; shs[1] = Bs[(k + 1) * 33 + k]; }
    }
    __syncthreads();
    float nx2 = shs[0], x0 = shs[1];
    if (nx2 < 1e-28f) {
      if (t == 0) ee[k] = x0;
      __syncthreads();
      continue;
    }
    if (t < 32) {
      float alpha = (x0 >= 0.f) ? -sqrtf(nx2) : sqrtf(nx2);
      float h = nx2 - alpha * x0;
      float xi = (t < m) ? Bs[(k + 1 + t) * 33 + k] : 0.f;
      float vi = (t == 0) ? (xi - alpha) : xi;
      vvs[t] = (t < m) ? vi : 0.f;
      if (t == 0) { ee[k] = alpha; shs[2] = h; }
    }
    __syncthreads();
    {
      int i = t >> 3, s = t & 7;
      float p = 0.f;
      if (i < m) {
        const float* rowp = &Bs[(k + 1 + i) * 33 + (k + 1)];
        for (int j = s; j < m; j += 8) p += rowp[j] * vvs[j];
      }
      part[t] = p;
    }
    __syncthreads();
    if (t < 64) {
      float h = shs[2];
      float pi = 0.f;
      if (t < 32) {
#pragma unroll
        for (int s = 0; s < 8; ++s) pi += part[t * 8 + s];
        pi /= h;
      }
      float vip = (t < 32) ? vvs[t] * pi : 0.f;
      float vp = wred(vip);
      float Kc = vp / (2.f * h);
      if (t < 32) uus[t] = (t < m) ? (pi - Kc * vvs[t]) : 0.f;
    }
    __syncthreads();
    for (int e = t; e < 1024; e += 256) {
      int i = e >> 5, j = e & 31;
      if (i < m && j < m)
        Bs[(k + 1 + i) * 33 + (k + 1 + j)] -= vvs[i] * uus[j] + uus[i] * vvs[j];
    }
    __syncthreads();
  }
  if (t < 32) dd[t] = Bs[t * 33 + t];
  if (t == 0) { ee[30] = Bs[31 * 33 + 30]; ee[31] = 0.f; }
  __syncthreads();
  if (t < 32) ee2[t] = (t < 31) ? ee[t] * ee[t] : 0.f;
  __syncthreads();
  if (t < 64) {
    int tt = t & 31;
    float di = dd[tt];
    float r = 0.f;
    if (tt > 0) r += fabsf(ee[tt - 1]);
    if (tt < 31) r += fabsf(ee[tt]);
    float lo = wredmin(di - r);
    float hi = wredmax(di + r);
    if (t == 0) { shs[0] = lo - 1e-6f; shs[1] = hi + 1e-6f; }
  }
  __syncthreads();
  if (t < 32) {
    float a = shs[0], b = shs[1];
    for (int it = 0; it < BIS_IT; ++it) {
      float mid = 0.5f * (a + b);
      float q = dd[0] - mid;
      int cnt = (q < 0.f) ? 1 : 0;
#pragma unroll
      for (int i = 1; i < 32; ++i) {
        float den = q;
        float ad = fabsf(den);
        den = (ad < 1e-30f) ? ((den < 0.f) ? -1e-30f : 1e-30f) : den;
        q = dd[i] - mid - ee2[i - 1] * __builtin_amdgcn_rcpf(den);
        cnt += (q < 0.f) ? 1 : 0;
      }
      if (cnt <= t) a = mid; else b = mid;
    }
    evs[t] = 0.5f * (a + b);
  }
  __syncthreads();
  if (t == 0) {
    int K = Kptr ? *Kptr : 10;
    if (K < 1) K = 10;
    if (K > 32) K = 32;
    float t12 = 0.f, t13 = 0.f, t23 = 0.f;
    for (int b = 0; b < 8; ++b) {
      float f1 = flags[b * 2 + 0] ? 1.f : 0.f;
      float f2 = flags[b * 2 + 1] ? 1.f : 0.f;
      for (int k = 0; k < K; ++k) {
        float v1 = (k == 0) ? 0.f : (k == 1 ? f1 : 1.f);
        float v2 = (k == 0) ? 0.f : (k == 1 ? f2 : 1.f);
        float m3 = 2.f - 2.f * evs[31 - k];
        t12 += (v1 - v2) * (v1 - v2);
        t13 += (v1 - m3) * (v1 - m3);
        t23 += (v2 - m3) * (v2 - m3);
      }
    }
    out[0] = 5.f * (t12 + t13 + t23) / (8.f * (float)K);
  }
}

// ------------- unified step dispatcher (identical in coop & fallback) -------
__device__ void do_step(int s, const float* F, const float4* G4, const float* R,
                        float* X0, float* XA, float* XB, float* GP,
                        const int* flags, const int* Kptr, float* out, int P,
                        float* LDSu, int bx, int t) {
  const int per = P_INNER + 2;
  float* FIN = (P_INNER & 1) ? XA : XB;  // buffer holding last inner-MV result
  if (s < 2 * per) {
    int ls = s % per;
    if (ls < P_INNER) {
      if (bx < 50 * P) {
        int rb = bx / P, jp = bx % P;
        const float* Xin; float* Xout; int npin;
        if (ls == 0)      { Xin = X0; npin = 1; Xout = XA; }
        else if (ls & 1)  { Xin = XA; npin = P; Xout = XB; }
        else              { Xin = XB; npin = P; Xout = XA; }
        mv_phase(F, G4, R, Xin, npin, Xout, rb, jp, P, LDSu, t);
      }
    } else if (ls == P_INNER) {
      if (bx < 25) gram_phase(FIN, P, FIN, P, GP, LDSu, bx, t);
    } else {
      if (bx < 200) apply_phase(GP, FIN, P, X0, LDSu, bx, t);
    }
  } else {
    int ls = s - 2 * per;
    if (ls == 0) {
      if (bx < 50 * P) {
        int rb = bx / P, jp = bx % P;
        mv_phase(F, G4, R, X0, 1, XA, rb, jp, P, LDSu, t);
      }
    } else if (ls == 1) {
      if (bx < 25) gram_phase(X0, 1, XA, P, GP, LDSu, bx, t);
    } else {
      if (bx == 0) rr_phase(GP, flags, Kptr, out, LDSu, t);
    }
  }
}

__global__ void __launch_bounds__(256)
k_solve(const float* F, const float4* G4, const float* R, float* X0,
        float* XA, float* XB, float* GP, const int* flags, const int* Kptr,
        float* out, int P, unsigned* bcnt, unsigned* bgen, unsigned nb) {
  __shared__ __align__(16) float LDSu[LDSF];
  const int bx = blockIdx.x, t = threadIdx.x;
  for (int s = 0; s < NSTEPS; ++s) {
    do_step(s, F, G4, R, X0, XA, XB, GP, flags, Kptr, out, P, LDSu, bx, t);
    if (s + 1 < NSTEPS) grid_barrier(bcnt, bgen, nb, t);
  }
}

__global__ void __launch_bounds__(256)
k_step(int s, const float* F, const float4* G4, const float* R, float* X0,
       float* XA, float* XB, float* GP, const int* flags, const int* Kptr,
       float* out, int P) {
  __shared__ __align__(16) float LDSu[LDSF];
  do_step(s, F, G4, R, X0, XA, XB, GP, flags, Kptr, out, P, LDSu,
          blockIdx.x, threadIdx.x);
}

extern "C" void kernel_launch(void* const* d_in, const int* in_sizes, int n_in,
                              void* d_out, int out_size, void* d_ws, size_t ws_size,
                              hipStream_t stream) {
  const float* feats = (const float*)d_in[0];
  const int* Kptr = (n_in > 1) ? (const int*)d_in[1] : nullptr;
  float* ws = (float*)d_ws;
  float* RZ = ws;                       // 38400 (dead after k_prep)
  float* GP = ws;                       // 25600 (overlay)
  float* Fb = ws + 38400;               // 4800
  float4* G4 = (float4*)(ws + 43200);   // 1600 float4
  float* Rb = ws + 49600;               // 1600
  int* FLAGS = (int*)(ws + 51200);      // 16 ints
  unsigned* BCNT = (unsigned*)(ws + 51216);  // barrier count (own line)
  unsigned* BGEN = (unsigned*)(ws + 51248);  // barrier gen (128 B away)
  float* X0 = ws + 51264;               // 51200
  float* XA = ws + 102464;              // P*51200
  const int P = (ws_size >= (size_t)(102464 + 2 * 5 * XPART) * 4) ? 5 : 1;
  float* XB = XA + (size_t)P * XPART;

  k_resize<<<dim3(7, 24), 256, 0, stream>>>(feats, RZ);
  k_prep<<<23, 256, 0, stream>>>(RZ, Fb, FLAGS);
  k_degree<<<100, 256, 0, stream>>>(Fb, Rb, G4, X0, BCNT, BGEN);

  const float* Fc = Fb;
  const float4* Gc = G4;
  const float* Rc = Rb;
  const int* FLc = FLAGS;
  float* outp = (float*)d_out;
  int Pv = P;
  unsigned nb = (unsigned)(50 * P);
  void* args[] = {(void*)&Fc, (void*)&Gc, (void*)&Rc, (void*)&X0, (void*)&XA,
                  (void*)&XB, (void*)&GP, (void*)&FLc, (void*)&Kptr,
                  (void*)&outp, (void*)&Pv, (void*)&BCNT, (void*)&BGEN,
                  (void*)&nb};
  hipError_t err = hipLaunchCooperativeKernel(
      (const void*)k_solve, dim3(50 * P, 1, 1), dim3(256, 1, 1), args, 0, stream);
  if (err != hipSuccess) {
    // fallback: identical phase sequence as separate launches
    for (int s = 0; s < NSTEPS; ++s)
      k_step<<<dim3(50 * P), 256, 0, stream>>>(s, Fc, Gc, Rc, X0, XA, XB, GP,
                                               FLc, Kptr, outp, Pv);
  }
}

// Round 8
// 703.165 us; speedup vs baseline: 16.7465x; 1.4404x over previous
//
#include <hip/hip_runtime.h>
#include <math.h>

#define N16 1600
#define M 32
#define T_OUTER 2
#define P_INNER 10
#define NSTEPS 27        // 10 MV, gram, apply, 10 MV, gram, apply, MV, gram, rr
#define BIS_IT 28
#define EPSF 1e-12f
#define XSZ 51200        // floats per X buffer
#define LDSF 8448
#define WST 68

// ---------------- device-scope (L2-bypass) access helpers -------------------
__device__ __forceinline__ float ldg_dev(const float* p) {
  return __hip_atomic_load(p, __ATOMIC_RELAXED, __HIP_MEMORY_SCOPE_AGENT);
}
__device__ __forceinline__ void stg_dev(float* p, float v) {
  __hip_atomic_store(p, v, __ATOMIC_RELAXED, __HIP_MEMORY_SCOPE_AGENT);
}

// ---------------- wave-wide butterfly reductions (64 lanes) -----------------
__device__ __forceinline__ float wred(float v) {
#pragma unroll
  for (int o = 32; o; o >>= 1) v += __shfl_xor(v, o, 64);
  return v;
}
__device__ __forceinline__ float wredmin(float v) {
#pragma unroll
  for (int o = 32; o; o >>= 1) v = fminf(v, __shfl_xor(v, o, 64));
  return v;
}
__device__ __forceinline__ float wredmax(float v) {
#pragma unroll
  for (int o = 32; o; o >>= 1) v = fmaxf(v, __shfl_xor(v, o, 64));
  return v;
}

// ---------------- fence-free grid barrier (all data is L2-bypassing) --------
__device__ __forceinline__ void grid_barrier(unsigned* cnt, unsigned* gen,
                                             unsigned nb, int t) {
  __threadfence_block();  // s_waitcnt vmcnt(0) lgkmcnt(0): this wave drained
  __syncthreads();        // + compiler-emitted vmcnt drain for all waves
  if (t == 0) {
    unsigned g = __hip_atomic_load(gen, __ATOMIC_RELAXED, __HIP_MEMORY_SCOPE_AGENT);
    unsigned a = __hip_atomic_fetch_add(cnt, 1u, __ATOMIC_RELAXED,
                                        __HIP_MEMORY_SCOPE_AGENT);
    if (a + 1u == nb) {
      __hip_atomic_store(cnt, 0u, __ATOMIC_RELAXED, __HIP_MEMORY_SCOPE_AGENT);
      __hip_atomic_store(gen, g + 1u, __ATOMIC_RELAXED, __HIP_MEMORY_SCOPE_AGENT);
    } else {
      while (__hip_atomic_load(gen, __ATOMIC_RELAXED,
                               __HIP_MEMORY_SCOPE_AGENT) == g)
        __builtin_amdgcn_s_sleep(1);
    }
  }
  __syncthreads();
}

// ---------------- resize (jax.image.resize bilinear, antialias=True) --------
__device__ inline void taps1d(int o, int* lo, int* hi, float* wsum, float w[8]) {
  int l = 4 * o - 2, h = 4 * o + 5;
  if (l < 0) l = 0;
  if (h > 159) h = 159;
  float c = 4.f * o + 1.5f, s = 0.f;
  for (int x = l; x <= h; ++x) {
    float ww = 1.f - fabsf((float)x - c) * 0.25f;
    w[x - l] = ww;
    s += ww;
  }
  *lo = l; *hi = h; *wsum = s;
}

__global__ void k_resize(const float* __restrict__ in, float* __restrict__ rz) {
  int map = blockIdx.y;
  int o = blockIdx.x * 256 + threadIdx.x;
  if (o >= N16) return;
  int oy = o / 40, ox = o % 40;
  int ly, hy, lx, hx; float sy, sx; float wy[8], wx[8];
  taps1d(oy, &ly, &hy, &sy, wy);
  taps1d(ox, &lx, &hx, &sx, wx);
  const float* src = in + (size_t)map * 160 * 160;
  float acc = 0.f;
  for (int y = ly; y <= hy; ++y) {
    float a = 0.f;
    const float* row = src + y * 160;
    for (int x = lx; x <= hx; ++x) a += wx[x - lx] * row[x];
    acc += wy[y - ly] * a;
  }
  rz[map * N16 + o] = acc / (sy * sx);
}

// ------------- prep: sign counts (lan1/lan2) + row-normalize sample0 --------
__global__ void k_prep(const float* __restrict__ rz, float* __restrict__ F,
                       int* __restrict__ flags) {
  __shared__ int sp[256], sn[256];
  int blk = blockIdx.x;
  if (blk < 16) {
    int b = blk >> 1, c = blk & 1;
    const float* m = rz + (b * 3 + c) * N16;
    int cp = 0, cn = 0;
    for (int o = threadIdx.x; o < N16; o += 256) {
      float v = m[o];
      cp += (v > 0.f);
      cn += (v < 0.f);
    }
    sp[threadIdx.x] = cp; sn[threadIdx.x] = cn;
    __syncthreads();
    for (int s = 128; s > 0; s >>= 1) {
      if (threadIdx.x < s) {
        sp[threadIdx.x] += sp[threadIdx.x + s];
        sn[threadIdx.x] += sn[threadIdx.x + s];
      }
      __syncthreads();
    }
    if (threadIdx.x == 0) flags[blk] = (sp[0] == 0 || sn[0] == 0) ? 1 : 0;
  } else {
    int n = (blk - 16) * 256 + threadIdx.x;
    if (n < N16) {
      float x = rz[n], y = rz[N16 + n], z = rz[2 * N16 + n];
      float nrm = sqrtf(x * x + y * y + z * z);
      float s = 1.f / fmaxf(nrm, EPSF);
      F[n * 3 + 0] = x * s; F[n * 3 + 1] = y * s; F[n * 3 + 2] = z * s;
    }
  }
}

// ------------- degree + G4 + X0 init + barrier/ring init (fused) ------------
__global__ void k_degree(const float* __restrict__ F, float* __restrict__ R,
                         float4* __restrict__ G4, float* __restrict__ X0,
                         float* __restrict__ Z1,
                         unsigned* __restrict__ bcnt, unsigned* __restrict__ bgen) {
  if (blockIdx.x == 0 && threadIdx.x == 0) {
    __hip_atomic_store(bcnt, 0u, __ATOMIC_RELAXED, __HIP_MEMORY_SCOPE_AGENT);
    __hip_atomic_store(bgen, 0u, __ATOMIC_RELAXED, __HIP_MEMORY_SCOPE_AGENT);
  }
  // zero first ring buffer (atomicAdd target of MV m=1)
  for (int e = threadIdx.x; e < 512; e += 256) Z1[blockIdx.x * 512 + e] = 0.f;
  __shared__ float Fl[4800];
  __shared__ float red[256];
  for (int t = threadIdx.x; t < 4800; t += 256) Fl[t] = F[t];
  __syncthreads();
  int rl = threadIdx.x >> 4, jt = threadIdx.x & 15;
  int i = blockIdx.x * 16 + rl;
  float fx = Fl[i * 3], fy = Fl[i * 3 + 1], fz = Fl[i * 3 + 2];
  float s = 0.f;
  for (int j = jt; j < N16; j += 16) {
    float w = fx * Fl[j * 3] + fy * Fl[j * 3 + 1] + fz * Fl[j * 3 + 2];
    if (w > 0.f) s += w;
  }
  red[threadIdx.x] = s;
  __syncthreads();
  for (int st = 8; st > 0; st >>= 1) {
    if (jt < st) red[threadIdx.x] += red[threadIdx.x + st];
    __syncthreads();
  }
  if (jt == 0) {
    float d = red[threadIdx.x];
    if (d < EPSF) d = 1.f;
    float r = rsqrtf(d);
    R[i] = r;
    float4 g; g.x = r * fx; g.y = r * fy; g.z = r * fz; g.w = 0.f;
    G4[i] = g;
  }
  for (int e = threadIdx.x; e < 512; e += 256) {
    int n = blockIdx.x * 16 + (e >> 5);
    int k = e & 31;
    unsigned u = ((unsigned)n * 2654435761u) ^ ((unsigned)k * 0x9E3779B9u);
    u = u * 1664525u + 1013904223u;
    u ^= u >> 16; u *= 2246822519u; u ^= u >> 13;
    X0[n * M + k] = ((float)(u >> 8) * (1.f / 8388608.f)) - 1.f;
  }
}

// ============== phase device functions ======================================

// Xout += 0.5*([jp==0]*Xin + S_jp Xin), atomicAdd into single buffer.
// Also zeroes Znext (jp==1) and optionally GP (jp==2, rb<4).
__device__ void mv_phase(const float* __restrict__ F, const float4* __restrict__ G4,
                         const float* __restrict__ R, const float* __restrict__ Xin,
                         float* __restrict__ Xout, float* __restrict__ Znext,
                         float* __restrict__ GPz, int rb, int jp,
                         float* LDSu, int t) {
  float* XsT = LDSu;          // [32][WST]
  float* Ws  = LDSu + 2176;   // [32][WST]
  float* Red = LDSu + 4352;   // [4][1024]
  const int rg = t & 7, kg = (t >> 3) & 7, jg = t >> 6;
  const int i0 = rb * 32;
  const int jlo = jp * 320;
  const int il = t & 31;
  const float fx = F[(i0 + il) * 3], fy = F[(i0 + il) * 3 + 1],
              fz = F[(i0 + il) * 3 + 2];
  float acc[4][4];
#pragma unroll
  for (int r = 0; r < 4; ++r)
#pragma unroll
    for (int kk = 0; kk < 4; ++kk) acc[r][kk] = 0.f;

  for (int c = 0; c < 5; ++c) {
    const int jbase = jlo + c * 64;
    __syncthreads();
    // stage XsT: device-scope dword loads (L2-bypass), transposed into LDS
#pragma unroll
    for (int it = 0; it < 2; ++it) {
      int e = it * 256 + t;            // 0..511
      int jl = e >> 3, kq = e & 7;
      const float* p = Xin + (size_t)(jbase + jl) * 32 + kq * 4;
      float v0 = ldg_dev(p + 0);
      float v1 = ldg_dev(p + 1);
      float v2 = ldg_dev(p + 2);
      float v3 = ldg_dev(p + 3);
      XsT[(kq * 4 + 0) * WST + jl] = v0;
      XsT[(kq * 4 + 1) * WST + jl] = v1;
      XsT[(kq * 4 + 2) * WST + jl] = v2;
      XsT[(kq * 4 + 3) * WST + jl] = v3;
    }
    // stage Ws (G4 normal cached loads — L2 stays warm, never invalidated)
#pragma unroll
    for (int it = 0; it < 8; ++it) {
      int jl = it * 8 + (t >> 5);
      float4 g = G4[jbase + jl];
      Ws[il * WST + jl] = fmaxf(fx * g.x + fy * g.y + fz * g.z, 0.f);
    }
    __syncthreads();
#pragma unroll
    for (int q = 0; q < 4; ++q) {
      const int jq = (jg * 4 + q) * 4;
      float4 wv[4], xv[4];
#pragma unroll
      for (int r = 0; r < 4; ++r)
        wv[r] = *(const float4*)&Ws[(rg + 8 * r) * WST + jq];
#pragma unroll
      for (int kk = 0; kk < 4; ++kk)
        xv[kk] = *(const float4*)&XsT[(kg + 8 * kk) * WST + jq];
#pragma unroll
      for (int r = 0; r < 4; ++r)
#pragma unroll
        for (int kk = 0; kk < 4; ++kk)
          acc[r][kk] += wv[r].x * xv[kk].x + wv[r].y * xv[kk].y +
                        wv[r].z * xv[kk].z + wv[r].w * xv[kk].w;
    }
  }
  __syncthreads();
#pragma unroll
  for (int r = 0; r < 4; ++r)
#pragma unroll
    for (int kk = 0; kk < 4; ++kk)
      Red[jg * 1024 + (rg + 8 * r) * 32 + (kg + 8 * kk)] = acc[r][kk];
  __syncthreads();
#pragma unroll
  for (int it = 0; it < 4; ++it) {
    int o = it * 256 + t;              // 0..1023
    int ilw = o >> 5, k = o & 31;
    int gi = i0 + ilw;
    float sv = Red[o] + Red[1024 + o] + Red[2048 + o] + Red[3072 + o];
    float val = 0.5f * R[gi] * sv;
    if (jp == 0) val += 0.5f * ldg_dev(Xin + (size_t)gi * 32 + k);
    atomicAdd(Xout + (size_t)gi * 32 + k, val);  // device-scope (m20)
  }
  // zero next ring buffer slice (rows of this rb), disjoint across blocks
  if (jp == 1) {
#pragma unroll
    for (int it = 0; it < 4; ++it)
      stg_dev(Znext + (size_t)i0 * 32 + it * 256 + t, 0.f);
  }
  if (GPz && jp == 2 && rb < 4) stg_dev(GPz + rb * 256 + t, 0.f);
}

// Gram: 25 blocks, atomicAdd partial products into zeroed GP[1024]
__device__ void gram_phase(const float* __restrict__ Xa, const float* __restrict__ Xb,
                           float* __restrict__ GP, float* LDSu, int bx, int t) {
  float* sA = LDSu;           // 2048
  float* sB = LDSu + 2048;    // 2048
  int j0 = bx * 64;
  for (int s = t; s < 64 * M; s += 256) {
    sA[s] = ldg_dev(Xa + (size_t)j0 * M + s);
    sB[s] = ldg_dev(Xb + (size_t)j0 * M + s);
  }
  __syncthreads();
  for (int s = 0; s < 4; ++s) {
    int e = s * 256 + t;
    int a = e >> 5, b = e & 31;
    float sum = 0.f;
    for (int jl = 0; jl < 64; ++jl) sum += sA[jl * M + a] * sB[jl * M + b];
    atomicAdd(GP + e, sum);
  }
}

// reduce none (GP is summed) + Cholesky + L^-1 + X0 <- X * L^-T (8 rows/blk)
__device__ void apply_phase(const float* __restrict__ GP,
                            const float* __restrict__ Xin,
                            float* __restrict__ Xout, float* LDSu, int bx, int t) {
  float* Gm = LDSu;            // 32*33
  float* LI = LDSu + 1056;     // 32*33
  float* Xsum = LDSu + 2112;   // 256
  for (int e = t; e < 1024; e += 256)
    Gm[(e >> 5) * 33 + (e & 31)] = ldg_dev(GP + e);
  const int row0 = bx * 8;
  Xsum[t] = ldg_dev(Xin + (size_t)row0 * M + t);
  __syncthreads();
  for (int k = 0; k < 32; ++k) {
    if (t == 0) Gm[k * 33 + k] = sqrtf(fmaxf(Gm[k * 33 + k], 1e-30f));
    __syncthreads();
    float piv = Gm[k * 33 + k];
    if (t > k && t < 32) Gm[t * 33 + k] /= piv;
    __syncthreads();
    for (int e = t; e < 1024; e += 256) {
      int i = e >> 5, j = e & 31;
      if (i > k && j > k && j <= i) Gm[i * 33 + j] -= Gm[i * 33 + k] * Gm[j * 33 + k];
    }
    __syncthreads();
  }
  if (t < 32) {
    int c = t;
    for (int i = c; i < 32; ++i) {
      float x = (i == c) ? 1.f : 0.f;
      for (int l = c; l < i; ++l) x -= Gm[i * 33 + l] * LI[c * 33 + l];
      LI[c * 33 + i] = x / Gm[i * 33 + i];
    }
  }
  __syncthreads();
  {
    int r = t >> 5, k = t & 31;
    float s = 0.f;
    for (int l = 0; l <= k; ++l) s += Xsum[r * M + l] * LI[l * 33 + k];
    stg_dev(Xout + (size_t)(row0 + r) * M + k, s);
  }
}

// Householder tridiag + Sturm bisection + final loss
__device__ void rr_phase(const float* __restrict__ GP,
                         const int* __restrict__ flags,
                         const int* __restrict__ Kptr,
                         float* __restrict__ out, float* Ph, int t) {
  float* Bs   = Ph;           // 1056
  float* part = Ph + 1056;    // 1024
  float* vvs  = Ph + 2080;
  float* uus  = Ph + 2112;
  float* dd   = Ph + 2144;
  float* ee   = Ph + 2176;
  float* ee2  = Ph + 2208;
  float* evs  = Ph + 2240;
  float* shs  = Ph + 2272;
  for (int e = t; e < 1024; e += 256) part[e] = ldg_dev(GP + e);
  __syncthreads();
  for (int e = t; e < 1024; e += 256) {
    int i = e >> 5, j = e & 31;
    Bs[i * 33 + j] = 0.5f * (part[e] + part[j * 32 + i]);
  }
  __syncthreads();
  for (int k = 0; k <= 29; ++k) {
    const int m = 31 - k;
    if (t < 64) {
      float xi = (t < m) ? Bs[(k + 1 + t) * 33 + k] : 0.f;
      float nx2 = wred(xi * xi);
      if (t == 0) { shs[0] = nx2; shs[1] = Bs[(k + 1) * 33 + k]; }
    }
    __syncthreads();
    float nx2 = shs[0], x0 = shs[1];
    if (nx2 < 1e-28f) {
      if (t == 0) ee[k] = x0;
      __syncthreads();
      continue;
    }
    if (t < 32) {
      float alpha = (x0 >= 0.f) ? -sqrtf(nx2) : sqrtf(nx2);
      float h = nx2 - alpha * x0;
      float xi = (t < m) ? Bs[(k + 1 + t) * 33 + k] : 0.f;
      float vi = (t == 0) ? (xi - alpha) : xi;
      vvs[t] = (t < m) ? vi : 0.f;
      if (t == 0) { ee[k] = alpha; shs[2] = h; }
    }
    __syncthreads();
    {
      int i = t >> 3, s = t & 7;
      float p = 0.f;
      if (i < m) {
        const float* rowp = &Bs[(k + 1 + i) * 33 + (k + 1)];
        for (int j = s; j < m; j += 8) p += rowp[j] * vvs[j];
      }
      part[t] = p;
    }
    __syncthreads();
    if (t < 64) {
      float h = shs[2];
      float pi = 0.f;
      if (t < 32) {
#pragma unroll
        for (int s = 0; s < 8; ++s) pi += part[t * 8 + s];
        pi /= h;
      }
      float vip = (t < 32) ? vvs[t] * pi : 0.f;
      float vp = wred(vip);
      float Kc = vp / (2.f * h);
      if (t < 32) uus[t] = (t < m) ? (pi - Kc * vvs[t]) : 0.f;
    }
    __syncthreads();
    for (int e = t; e < 1024; e += 256) {
      int i = e >> 5, j = e & 31;
      if (i < m && j < m)
        Bs[(k + 1 + i) * 33 + (k + 1 + j)] -= vvs[i] * uus[j] + uus[i] * vvs[j];
    }
    __syncthreads();
  }
  if (t < 32) dd[t] = Bs[t * 33 + t];
  if (t == 0) { ee[30] = Bs[31 * 33 + 30]; ee[31] = 0.f; }
  __syncthreads();
  if (t < 32) ee2[t] = (t < 31) ? ee[t] * ee[t] : 0.f;
  __syncthreads();
  if (t < 64) {
    int tt = t & 31;
    float di = dd[tt];
    float r = 0.f;
    if (tt > 0) r += fabsf(ee[tt - 1]);
    if (tt < 31) r += fabsf(ee[tt]);
    float lo = wredmin(di - r);
    float hi = wredmax(di + r);
    if (t == 0) { shs[0] = lo - 1e-6f; shs[1] = hi + 1e-6f; }
  }
  __syncthreads();
  if (t < 32) {
    float a = shs[0], b = shs[1];
    for (int it = 0; it < BIS_IT; ++it) {
      float mid = 0.5f * (a + b);
      float q = dd[0] - mid;
      int cnt = (q < 0.f) ? 1 : 0;
#pragma unroll
      for (int i = 1; i < 32; ++i) {
        float den = q;
        float ad = fabsf(den);
        den = (ad < 1e-30f) ? ((den < 0.f) ? -1e-30f : 1e-30f) : den;
        q = dd[i] - mid - ee2[i - 1] * __builtin_amdgcn_rcpf(den);
        cnt += (q < 0.f) ? 1 : 0;
      }
      if (cnt <= t) a = mid; else b = mid;
    }
    evs[t] = 0.5f * (a + b);
  }
  __syncthreads();
  if (t == 0) {
    int K = Kptr ? *Kptr : 10;
    if (K < 1) K = 10;
    if (K > 32) K = 32;
    float t12 = 0.f, t13 = 0.f, t23 = 0.f;
    for (int b = 0; b < 8; ++b) {
      float f1 = flags[b * 2 + 0] ? 1.f : 0.f;
      float f2 = flags[b * 2 + 1] ? 1.f : 0.f;
      for (int k = 0; k < K; ++k) {
        float v1 = (k == 0) ? 0.f : (k == 1 ? f1 : 1.f);
        float v2 = (k == 0) ? 0.f : (k == 1 ? f2 : 1.f);
        float m3 = 2.f - 2.f * evs[31 - k];
        t12 += (v1 - v2) * (v1 - v2);
        t13 += (v1 - m3) * (v1 - m3);
        t23 += (v2 - m3) * (v2 - m3);
      }
    }
    out[0] = 5.f * (t12 + t13 + t23) / (8.f * (float)K);
  }
}

// ------------- unified step dispatcher --------------------------------------
// s: 0-9 MV m=1..10 | 10 gram | 11 apply | 12-21 MV m=11..20 | 22 gram |
//    23 apply | 24 MV m=21 | 25 gram(X0,AX0) | 26 rr
__device__ void do_step(int s, const float* F, const float4* G4, const float* R,
                        float* X0, float* Z0, float* Z1, float* Z2,
                        float* GP, const int* flags, const int* Kptr, float* out,
                        float* LDSu, int bx, int t) {
  float* Zr[3] = {Z0, Z1, Z2};
  if (s == 26) {
    if (bx == 0) rr_phase(GP, flags, Kptr, out, LDSu, t);
    return;
  }
  if (s == 10 || s == 22 || s == 25) {
    if (bx < 25) {
      const float *Xa, *Xb;
      if (s == 10) { Xa = Z1; Xb = Z1; }          // m=10 output
      else if (s == 22) { Xa = Z2; Xb = Z2; }     // m=20 output
      else { Xa = X0; Xb = Z0; }                  // final: X0^T (A X0)
      gram_phase(Xa, Xb, GP, LDSu, bx, t);
    }
    return;
  }
  if (s == 11 || s == 23) {
    if (bx < 200) apply_phase(GP, (s == 11) ? Z1 : Z2, X0, LDSu, bx, t);
    return;
  }
  int m = (s < 10) ? (s + 1) : ((s < 22) ? (s - 1) : 21);
  const float* Xin = (m == 1 || m == 11 || m == 21) ? X0 : Zr[(m - 1) % 3];
  float* Xout = Zr[m % 3];
  float* Znx = Zr[(m + 1) % 3];
  float* GPz = (m == 10 || m == 20 || m == 21) ? GP : nullptr;
  mv_phase(F, G4, R, Xin, Xout, Znx, GPz, bx / 5, bx % 5, LDSu, t);
}

__global__ void __launch_bounds__(256)
k_solve(const float* F, const float4* G4, const float* R, float* X0,
        float* Z0, float* Z1, float* Z2, float* GP, const int* flags,
        const int* Kptr, float* out, unsigned* bcnt, unsigned* bgen,
        unsigned nb) {
  __shared__ __align__(16) float LDSu[LDSF];
  const int bx = blockIdx.x, t = threadIdx.x;
  for (int s = 0; s < NSTEPS; ++s) {
    do_step(s, F, G4, R, X0, Z0, Z1, Z2, GP, flags, Kptr, out, LDSu, bx, t);
    if (s + 1 < NSTEPS) grid_barrier(bcnt, bgen, nb, t);
  }
}

__global__ void __launch_bounds__(256)
k_step(int s, const float* F, const float4* G4, const float* R, float* X0,
       float* Z0, float* Z1, float* Z2, float* GP, const int* flags,
       const int* Kptr, float* out) {
  __shared__ __align__(16) float LDSu[LDSF];
  do_step(s, F, G4, R, X0, Z0, Z1, Z2, GP, flags, Kptr, out, LDSu,
          blockIdx.x, threadIdx.x);
}

extern "C" void kernel_launch(void* const* d_in, const int* in_sizes, int n_in,
                              void* d_out, int out_size, void* d_ws, size_t ws_size,
                              hipStream_t stream) {
  const float* feats = (const float*)d_in[0];
  const int* Kptr = (n_in > 1) ? (const int*)d_in[1] : nullptr;
  float* ws = (float*)d_ws;
  float* RZ = ws;                       // 38400 (dead after k_prep)
  float* GP = ws;                       // 1024  (overlay)
  float* Fb = ws + 38400;               // 4800
  float4* G4 = (float4*)(ws + 43200);   // 1600 float4
  float* Rb = ws + 49600;               // 1600
  int* FLAGS = (int*)(ws + 51200);      // 16 ints
  unsigned* BCNT = (unsigned*)(ws + 51216);
  unsigned* BGEN = (unsigned*)(ws + 51248);
  float* X0 = ws + 51264;               // 51200
  float* Z0 = ws + 102464;              // 51200
  float* Z1 = ws + 153664;              // 51200
  float* Z2 = ws + 204864;              // 51200  (end 256064 floats ~1.02 MB)

  k_resize<<<dim3(7, 24), 256, 0, stream>>>(feats, RZ);
  k_prep<<<23, 256, 0, stream>>>(RZ, Fb, FLAGS);
  k_degree<<<100, 256, 0, stream>>>(Fb, Rb, G4, X0, Z1, BCNT, BGEN);

  const float* Fc = Fb;
  const float4* Gc = G4;
  const float* Rc = Rb;
  const int* FLc = FLAGS;
  float* outp = (float*)d_out;
  unsigned nb = 250u;
  void* args[] = {(void*)&Fc, (void*)&Gc, (void*)&Rc, (void*)&X0, (void*)&Z0,
                  (void*)&Z1, (void*)&Z2, (void*)&GP, (void*)&FLc, (void*)&Kptr,
                  (void*)&outp, (void*)&BCNT, (void*)&BGEN, (void*)&nb};
  hipError_t err = hipLaunchCooperativeKernel(
      (const void*)k_solve, dim3(250, 1, 1), dim3(256, 1, 1), args, 0, stream);
  if (err != hipSuccess) {
    for (int s = 0; s < NSTEPS; ++s)
      k_step<<<dim3(250), 256, 0, stream>>>(s, Fc, Gc, Rc, X0, Z0, Z1, Z2, GP,
                                            FLc, Kptr, outp);
  }
}

// Round 10
// 670.128 us; speedup vs baseline: 17.5720x; 1.0493x over previous
//
#include <hip/hip_runtime.h>
#include <math.h>

#define N16 1600
#define M 32
#define XSZ 51200
#define LDSF 8448
#define WST 68
#define BIS_IT 28
#define EPSF 1e-12f
#define NPH 30   // 0 resize+zero | 1 prep | 2 degree | 3-12 MV1-10 | 13 gram |
                 // 14 apply | 15-24 MV11-20 | 25 gram | 26 apply | 27 MV21 |
                 // 28 gram | 29 rr

// ---------------- device-scope (L3-level) access helpers --------------------
__device__ __forceinline__ float ldg_dev(const float* p) {
  return __hip_atomic_load(p, __ATOMIC_RELAXED, __HIP_MEMORY_SCOPE_AGENT);
}
__device__ __forceinline__ void stg_dev(float* p, float v) {
  __hip_atomic_store(p, v, __ATOMIC_RELAXED, __HIP_MEMORY_SCOPE_AGENT);
}
__device__ __forceinline__ void stg_devi(int* p, int v) {
  __hip_atomic_store(p, v, __ATOMIC_RELAXED, __HIP_MEMORY_SCOPE_AGENT);
}

// ---------------- wave reductions -------------------------------------------
__device__ __forceinline__ float wred(float v) {
#pragma unroll
  for (int o = 32; o; o >>= 1) v += __shfl_xor(v, o, 64);
  return v;
}
__device__ __forceinline__ float wredmin(float v) {
#pragma unroll
  for (int o = 32; o; o >>= 1) v = fminf(v, __shfl_xor(v, o, 64));
  return v;
}
__device__ __forceinline__ float wredmax(float v) {
#pragma unroll
  for (int o = 32; o; o >>= 1) v = fmaxf(v, __shfl_xor(v, o, 64));
  return v;
}

// ---------------- grid barrier (R8-proven, relaxed agent scope) -------------
__device__ __forceinline__ void grid_barrier(unsigned* cnt, unsigned* gen,
                                             unsigned nb, int t) {
  __threadfence_block();
  __syncthreads();
  if (t == 0) {
    unsigned g = __hip_atomic_load(gen, __ATOMIC_RELAXED, __HIP_MEMORY_SCOPE_AGENT);
    unsigned a = __hip_atomic_fetch_add(cnt, 1u, __ATOMIC_RELAXED,
                                        __HIP_MEMORY_SCOPE_AGENT);
    if (a + 1u == nb) {
      __hip_atomic_store(cnt, 0u, __ATOMIC_RELAXED, __HIP_MEMORY_SCOPE_AGENT);
      __hip_atomic_store(gen, g + 1u, __ATOMIC_RELAXED, __HIP_MEMORY_SCOPE_AGENT);
    } else {
      while (__hip_atomic_load(gen, __ATOMIC_RELAXED,
                               __HIP_MEMORY_SCOPE_AGENT) == g)
        __builtin_amdgcn_s_sleep(1);
    }
  }
  __syncthreads();
}

// ---------------- phase: resize (bx<168) + zero buffers (bx>=168) -----------
__device__ void taps1d(int o, int* lo, int* hi, float* wsum, float w[8]) {
  int l = 4 * o - 2, h = 4 * o + 5;
  if (l < 0) l = 0;
  if (h > 159) h = 159;
  float c = 4.f * o + 1.5f, s = 0.f;
  for (int x = l; x <= h; ++x) {
    float ww = 1.f - fabsf((float)x - c) * 0.25f;
    w[x - l] = ww;
    s += ww;
  }
  *lo = l; *hi = h; *wsum = s;
}

__device__ void resize_phase(const float* __restrict__ in, float* __restrict__ rz,
                             int bx, int t) {
  int map = bx / 7;
  int o = (bx % 7) * 256 + t;
  if (o >= N16) return;
  int oy = o / 40, ox = o % 40;
  int ly, hy, lx, hx; float sy, sx; float wy[8], wx[8];
  taps1d(oy, &ly, &hy, &sy, wy);
  taps1d(ox, &lx, &hx, &sx, wx);
  const float* src = in + (size_t)map * 160 * 160;
  float acc = 0.f;
  for (int y = ly; y <= hy; ++y) {
    float a = 0.f;
    const float* row = src + y * 160;
    for (int x = lx; x <= hx; ++x) a += wx[x - lx] * row[x];
    acc += wy[y - ly] * a;
  }
  stg_dev(rz + map * N16 + o, acc / (sy * sx));
}

__device__ void zero_phase(float* __restrict__ XB, float* __restrict__ GPb,
                           int mode, int bx, int t) {
  int tid = (bx - 168) * 256 + t;
  const int stride = 82 * 256;
  float* base = XB + (size_t)(mode ? 3 : 1) * XSZ;
  size_t len = (size_t)(mode ? 21 : 3) * XSZ;
  for (size_t i = tid; i < len; i += stride) stg_dev(base + i, 0.f);
  for (int i = tid; i < 3072; i += stride) stg_dev(GPb + i, 0.f);
}

// ---------------- phase: prep (bx<23) ---------------------------------------
__device__ void prep_phase(const float* __restrict__ rz, float* __restrict__ F,
                           int* __restrict__ flags, float* LDSu, int bx, int t) {
  int* sp = (int*)LDSu;
  int* sn = sp + 256;
  if (bx < 16) {
    int b = bx >> 1, c = bx & 1;
    const float* m = rz + (b * 3 + c) * N16;
    int cp = 0, cn = 0;
    for (int o = t; o < N16; o += 256) {
      float v = m[o];
      cp += (v > 0.f);
      cn += (v < 0.f);
    }
    sp[t] = cp; sn[t] = cn;
    __syncthreads();
    for (int s = 128; s > 0; s >>= 1) {
      if (t < s) { sp[t] += sp[t + s]; sn[t] += sn[t + s]; }
      __syncthreads();
    }
    if (t == 0) stg_devi(flags + bx, (sp[0] == 0 || sn[0] == 0) ? 1 : 0);
  } else if (bx < 23) {
    int n = (bx - 16) * 256 + t;
    if (n < N16) {
      float x = rz[n], y = rz[N16 + n], z = rz[2 * N16 + n];
      float nrm = sqrtf(x * x + y * y + z * z);
      float s = 1.f / fmaxf(nrm, EPSF);
      stg_dev(F + n * 3 + 0, x * s);
      stg_dev(F + n * 3 + 1, y * s);
      stg_dev(F + n * 3 + 2, z * s);
    }
  }
}

// ---------------- phase: degree + G4 + X0 init (bx<100) ---------------------
__device__ void degree_phase(const float* __restrict__ F, float* __restrict__ R,
                             float* __restrict__ G4f, float* __restrict__ X0,
                             float* LDSu, int bx, int t) {
  float* Fl = LDSu;          // 4800
  float* red = LDSu + 4800;  // 256
  for (int s = t; s < 4800; s += 256) Fl[s] = F[s];
  __syncthreads();
  int rl = t >> 4, jt = t & 15;
  int i = bx * 16 + rl;
  float fx = Fl[i * 3], fy = Fl[i * 3 + 1], fz = Fl[i * 3 + 2];
  float s = 0.f;
  for (int j = jt; j < N16; j += 16) {
    float w = fx * Fl[j * 3] + fy * Fl[j * 3 + 1] + fz * Fl[j * 3 + 2];
    if (w > 0.f) s += w;
  }
  red[t] = s;
  __syncthreads();
  for (int st = 8; st > 0; st >>= 1) {
    if (jt < st) red[t] += red[t + st];
    __syncthreads();
  }
  if (jt == 0) {
    float d = red[t];
    if (d < EPSF) d = 1.f;
    float r = rsqrtf(d);
    stg_dev(R + i, r);
    stg_dev(G4f + i * 4 + 0, r * fx);
    stg_dev(G4f + i * 4 + 1, r * fy);
    stg_dev(G4f + i * 4 + 2, r * fz);
    stg_dev(G4f + i * 4 + 3, 0.f);
  }
  for (int e = t; e < 512; e += 256) {
    int n = bx * 16 + (e >> 5);
    int k = e & 31;
    unsigned u = ((unsigned)n * 2654435761u) ^ ((unsigned)k * 0x9E3779B9u);
    u = u * 1664525u + 1013904223u;
    u ^= u >> 16; u *= 2246822519u; u ^= u >> 13;
    stg_dev(X0 + n * M + k, ((float)(u >> 8) * (1.f / 8388608.f)) - 1.f);
  }
}

// ---------------- phase: MV -------------------------------------------------
__device__ void mv_phase(const float* __restrict__ F, const float4* __restrict__ G4,
                         const float* __restrict__ R, const float* __restrict__ Xin,
                         float* __restrict__ Xout, float* __restrict__ Znext,
                         int rb, int jp, int cached, float* LDSu, int t) {
  float* XsT = LDSu;          // [32][WST]
  float* Ws  = LDSu + 2176;   // [32][WST]
  float* Red = LDSu + 4352;   // [4][1024]
  const int rg = t & 7, kg = (t >> 3) & 7, jg = t >> 6;
  const int i0 = rb * 32;
  const int jlo = jp * 320;
  const int il = t & 31;
  const float fx = F[(i0 + il) * 3], fy = F[(i0 + il) * 3 + 1],
              fz = F[(i0 + il) * 3 + 2];
  float acc[4][4];
#pragma unroll
  for (int r = 0; r < 4; ++r)
#pragma unroll
    for (int kk = 0; kk < 4; ++kk) acc[r][kk] = 0.f;

  for (int c = 0; c < 5; ++c) {
    const int jbase = jlo + c * 64;
    __syncthreads();
    if (cached) {
#pragma unroll
      for (int it = 0; it < 2; ++it) {
        int e = it * 256 + t;           // 0..511
        int row = e >> 3, q = e & 7;
        float4 v = *((const float4*)(Xin + (size_t)(jbase + row) * 32) + q);
        XsT[(q * 4 + 0) * WST + row] = v.x;
        XsT[(q * 4 + 1) * WST + row] = v.y;
        XsT[(q * 4 + 2) * WST + row] = v.z;
        XsT[(q * 4 + 3) * WST + row] = v.w;
      }
    } else {
#pragma unroll
      for (int it = 0; it < 2; ++it) {
        int e = it * 256 + t;
        int row = e >> 3, q = e & 7;
        const float* p = Xin + (size_t)(jbase + row) * 32 + q * 4;
        float v0 = ldg_dev(p + 0);
        float v1 = ldg_dev(p + 1);
        float v2 = ldg_dev(p + 2);
        float v3 = ldg_dev(p + 3);
        XsT[(q * 4 + 0) * WST + row] = v0;
        XsT[(q * 4 + 1) * WST + row] = v1;
        XsT[(q * 4 + 2) * WST + row] = v2;
        XsT[(q * 4 + 3) * WST + row] = v3;
      }
    }
#pragma unroll
    for (int it = 0; it < 8; ++it) {
      int jl = it * 8 + (t >> 5);
      float4 g = G4[jbase + jl];
      Ws[il * WST + jl] = fmaxf(fx * g.x + fy * g.y + fz * g.z, 0.f);
    }
    __syncthreads();
#pragma unroll
    for (int q = 0; q < 4; ++q) {
      const int jq = (jg * 4 + q) * 4;
      float4 wv[4], xv[4];
#pragma unroll
      for (int r = 0; r < 4; ++r)
        wv[r] = *(const float4*)&Ws[(rg + 8 * r) * WST + jq];
#pragma unroll
      for (int kk = 0; kk < 4; ++kk)
        xv[kk] = *(const float4*)&XsT[(kg + 8 * kk) * WST + jq];
#pragma unroll
      for (int r = 0; r < 4; ++r)
#pragma unroll
        for (int kk = 0; kk < 4; ++kk)
          acc[r][kk] += wv[r].x * xv[kk].x + wv[r].y * xv[kk].y +
                        wv[r].z * xv[kk].z + wv[r].w * xv[kk].w;
    }
  }
  __syncthreads();
#pragma unroll
  for (int r = 0; r < 4; ++r)
#pragma unroll
    for (int kk = 0; kk < 4; ++kk)
      Red[jg * 1024 + (rg + 8 * r) * 32 + (kg + 8 * kk)] = acc[r][kk];
  __syncthreads();
#pragma unroll
  for (int it = 0; it < 4; ++it) {
    int o = it * 256 + t;
    int ilw = o >> 5, k = o & 31;
    int gi = i0 + ilw;
    float sv = Red[o] + Red[1024 + o] + Red[2048 + o] + Red[3072 + o];
    float val = 0.5f * R[gi] * sv;
    if (jp == 0) val += 0.5f * ldg_dev(Xin + (size_t)gi * 32 + k);
    atomicAdd(Xout + (size_t)gi * 32 + k, val);
  }
  if (Znext && jp == 1) {
#pragma unroll
    for (int it = 0; it < 4; ++it)
      stg_dev(Znext + (size_t)i0 * 32 + it * 256 + t, 0.f);
  }
}

// ---------------- phase: gram (bx<25) ---------------------------------------
__device__ void gram_phase(const float* __restrict__ Xa, const float* __restrict__ Xb,
                           float* __restrict__ GP, float* LDSu, int bx, int t) {
  float* sA = LDSu;
  float* sB = LDSu + 2048;
  int j0 = bx * 64;
  for (int s = t; s < 64 * M; s += 256) {
    sA[s] = ldg_dev(Xa + (size_t)j0 * M + s);
    sB[s] = ldg_dev(Xb + (size_t)j0 * M + s);
  }
  __syncthreads();
  for (int s = 0; s < 4; ++s) {
    int e = s * 256 + t;
    int a = e >> 5, b = e & 31;
    float sum = 0.f;
    for (int jl = 0; jl < 64; ++jl) sum += sA[jl * M + a] * sB[jl * M + b];
    atomicAdd(GP + e, sum);
  }
}

// ---------------- phase: apply (bx<200): chol + register trisolve -----------
__device__ void apply_phase(const float* __restrict__ GP,
                            const float* __restrict__ Xin,
                            float* __restrict__ Xout, float* LDSu, int bx, int t) {
  float* Gm = LDSu;  // 32*33
  for (int e = t; e < 1024; e += 256)
    Gm[(e >> 5) * 33 + (e & 31)] = ldg_dev(GP + e);
  const int r = t >> 5, l = t & 31;
  const int row = bx * 8 + r;
  float x = ldg_dev(Xin + (size_t)row * M + l);
  __syncthreads();
  // Cholesky (lower, stride 33)
  for (int k = 0; k < 32; ++k) {
    if (t == 0) Gm[k * 33 + k] = sqrtf(fmaxf(Gm[k * 33 + k], 1e-30f));
    __syncthreads();
    float piv = Gm[k * 33 + k];
    if (t > k && t < 32) Gm[t * 33 + k] /= piv;
    __syncthreads();
    for (int e = t; e < 1024; e += 256) {
      int i = e >> 5, j = e & 31;
      if (i > k && j > k && j <= i) Gm[i * 33 + j] -= Gm[i * 33 + k] * Gm[j * 33 + k];
    }
    __syncthreads();
  }
  // solve y L^T = x per row; y_l distributed over 32-lane groups
  const int half = t & 32;
  float y = 0.f;
  for (int k = 0; k < 32; ++k) {
    float gkl = Gm[k * 33 + l];
    float contrib = (l < k) ? y * gkl : 0.f;
#pragma unroll
    for (int o = 16; o; o >>= 1) contrib += __shfl_xor(contrib, o, 64);
    float xk = __shfl(x, half + k, 64);
    float yk = (xk - contrib) / Gm[k * 33 + k];
    if (l == k) y = yk;
  }
  stg_dev(Xout + (size_t)row * M + l, y);
}

// ---------------- phase: rr (bx==0) -----------------------------------------
__device__ void rr_phase(const float* __restrict__ GP,
                         const int* __restrict__ flags,
                         const int* __restrict__ Kptr,
                         float* __restrict__ out, float* Ph, int t) {
  float* Bs   = Ph;
  float* part = Ph + 1056;
  float* vvs  = Ph + 2080;
  float* uus  = Ph + 2112;
  float* dd   = Ph + 2144;
  float* ee   = Ph + 2176;
  float* ee2  = Ph + 2208;
  float* evs  = Ph + 2240;
  float* shs  = Ph + 2272;
  for (int e = t; e < 1024; e += 256) part[e] = ldg_dev(GP + e);
  __syncthreads();
  for (int e = t; e < 1024; e += 256) {
    int i = e >> 5, j = e & 31;
    Bs[i * 33 + j] = 0.5f * (part[e] + part[j * 32 + i]);
  }
  __syncthreads();
  for (int k = 0; k <= 29; ++k) {
    const int m = 31 - k;
    if (t < 64) {
      float xi = (t < m) ? Bs[(k + 1 + t) * 33 + k] : 0.f;
      float nx2 = wred(xi * xi);
      if (t == 0) { shs[0] = nx2; shs[1] = Bs[(k + 1) * 33 + k]; }
    }
    __syncthreads();
    float nx2 = shs[0], x0 = shs[1];
    if (nx2 < 1e-28f) {
      if (t == 0) ee[k] = x0;
      __syncthreads();
      continue;
    }
    if (t < 32) {
      float alpha = (x0 >= 0.f) ? -sqrtf(nx2) : sqrtf(nx2);
      float h = nx2 - alpha * x0;
      float xi = (t < m) ? Bs[(k + 1 + t) * 33 + k] : 0.f;
      float vi = (t == 0) ? (xi - alpha) : xi;
      vvs[t] = (t < m) ? vi : 0.f;
      if (t == 0) { ee[k] = alpha; shs[2] = h; }
    }
    __syncthreads();
    {
      int i = t >> 3, s = t & 7;
      float p = 0.f;
      if (i < m) {
        const float* rowp = &Bs[(k + 1 + i) * 33 + (k + 1)];
        for (int j = s; j < m; j += 8) p += rowp[j] * vvs[j];
      }
      part[t] = p;
    }
    __syncthreads();
    if (t < 64) {
      float h = shs[2];
      float pi = 0.f;
      if (t < 32) {
#pragma unroll
        for (int s = 0; s < 8; ++s) pi += part[t * 8 + s];
        pi /= h;
      }
      float vip = (t < 32) ? vvs[t] * pi : 0.f;
      float vp = wred(vip);
      float Kc = vp / (2.f * h);
      if (t < 32) uus[t] = (t < m) ? (pi - Kc * vvs[t]) : 0.f;
    }
    __syncthreads();
    for (int e = t; e < 1024; e += 256) {
      int i = e >> 5, j = e & 31;
      if (i < m && j < m)
        Bs[(k + 1 + i) * 33 + (k + 1 + j)] -= vvs[i] * uus[j] + uus[i] * vvs[j];
    }
    __syncthreads();
  }
  if (t < 32) dd[t] = Bs[t * 33 + t];
  if (t == 0) { ee[30] = Bs[31 * 33 + 30]; ee[31] = 0.f; }
  __syncthreads();
  if (t < 32) ee2[t] = (t < 31) ? ee[t] * ee[t] : 0.f;
  __syncthreads();
  if (t < 64) {
    int tt = t & 31;
    float di = dd[tt];
    float r = 0.f;
    if (tt > 0) r += fabsf(ee[tt - 1]);
    if (tt < 31) r += fabsf(ee[tt]);
    float lo = wredmin(di - r);
    float hi = wredmax(di + r);
    if (t == 0) { shs[0] = lo - 1e-6f; shs[1] = hi + 1e-6f; }
  }
  __syncthreads();
  if (t < 32) {
    float a = shs[0], b = shs[1];
    for (int it = 0; it < BIS_IT; ++it) {
      float mid = 0.5f * (a + b);
      float q = dd[0] - mid;
      int cnt = (q < 0.f) ? 1 : 0;
#pragma unroll
      for (int i = 1; i < 32; ++i) {
        float den = q;
        float ad = fabsf(den);
        den = (ad < 1e-30f) ? ((den < 0.f) ? -1e-30f : 1e-30f) : den;
        q = dd[i] - mid - ee2[i - 1] * __builtin_amdgcn_rcpf(den);
        cnt += (q < 0.f) ? 1 : 0;
      }
      if (cnt <= t) a = mid; else b = mid;
    }
    evs[t] = 0.5f * (a + b);
  }
  __syncthreads();
  if (t == 0) {
    int K = Kptr ? *Kptr : 10;
    if (K < 1) K = 10;
    if (K > 32) K = 32;
    float t12 = 0.f, t13 = 0.f, t23 = 0.f;
    for (int b = 0; b < 8; ++b) {
      float f1 = flags[b * 2 + 0] ? 1.f : 0.f;
      float f2 = flags[b * 2 + 1] ? 1.f : 0.f;
      for (int k = 0; k < K; ++k) {
        float v1 = (k == 0) ? 0.f : (k == 1 ? f1 : 1.f);
        float v2 = (k == 0) ? 0.f : (k == 1 ? f2 : 1.f);
        float m3 = 2.f - 2.f * evs[31 - k];
        t12 += (v1 - v2) * (v1 - v2);
        t13 += (v1 - m3) * (v1 - m3);
        t23 += (v2 - m3) * (v2 - m3);
      }
    }
    out[0] = 5.f * (t12 + t13 + t23) / (8.f * (float)K);
  }
}

// ---------------- unified step dispatcher -----------------------------------
__device__ __forceinline__ float* bbuf(float* XB, int mode, int m) {
  return XB + (size_t)(mode ? (2 + m) : (1 + m % 3)) * XSZ;  // B_m
}

__device__ void do_step(int s, const float* feats, float* RZ, float* F,
                        float* G4f, float* R, int* flags, float* GPb, float* XB,
                        const int* Kptr, float* out, int mode,
                        float* LDSu, int bx, int t) {
  float* XV0 = XB;
  float* XV1 = XB + (size_t)(mode ? 1 : 0) * XSZ;
  float* XV2 = XB + (size_t)(mode ? 2 : 0) * XSZ;
  const float4* G4 = (const float4*)G4f;
  if (s == 0) {
    if (bx < 168) resize_phase(feats, RZ, bx, t);
    else zero_phase(XB, GPb, mode, bx, t);
    return;
  }
  if (s == 1) { prep_phase(RZ, F, flags, LDSu, bx, t); return; }
  if (s == 2) { if (bx < 100) degree_phase(F, R, G4f, XV0, LDSu, bx, t); return; }
  if (s == 13) { if (bx < 25) gram_phase(bbuf(XB, mode, 10), bbuf(XB, mode, 10), GPb, LDSu, bx, t); return; }
  if (s == 14) { if (bx < 200) apply_phase(GPb, bbuf(XB, mode, 10), XV1, LDSu, bx, t); return; }
  if (s == 25) { if (bx < 25) gram_phase(bbuf(XB, mode, 20), bbuf(XB, mode, 20), GPb + 1024, LDSu, bx, t); return; }
  if (s == 26) { if (bx < 200) apply_phase(GPb + 1024, bbuf(XB, mode, 20), XV2, LDSu, bx, t); return; }
  if (s == 28) { if (bx < 25) gram_phase(XV2, bbuf(XB, mode, 21), GPb + 2048, LDSu, bx, t); return; }
  if (s == 29) { if (bx == 0) rr_phase(GPb + 2048, flags, Kptr, out, LDSu, t); return; }
  // MV phases
  int m;
  const float* Xin;
  if (s >= 3 && s <= 12) { m = s - 2; Xin = (m == 1) ? XV0 : bbuf(XB, mode, m - 1); }
  else if (s >= 15 && s <= 24) { m = s - 4; Xin = (m == 11) ? XV1 : bbuf(XB, mode, m - 1); }
  else { m = 21; Xin = XV2; }
  float* Xout = bbuf(XB, mode, m);
  float* Znext = (!mode && m < 21) ? bbuf(XB, mode, m + 1) : nullptr;
  mv_phase(F, G4, R, Xin, Xout, Znext, bx / 5, bx % 5, mode, LDSu, t);
}

__global__ void __launch_bounds__(256)
k_solve(const float* feats, float* RZ, float* F, float* G4f, float* R,
        int* flags, float* GPb, float* XB, const int* Kptr, float* out,
        int mode, unsigned* bcnt, unsigned* bgen) {
  __shared__ __align__(16) float LDSu[LDSF];
  const int bx = blockIdx.x, t = threadIdx.x;
  for (int s = 0; s < NPH; ++s) {
    do_step(s, feats, RZ, F, G4f, R, flags, GPb, XB, Kptr, out, mode, LDSu, bx, t);
    if (s + 1 < NPH) grid_barrier(bcnt, bgen, 250u, t);
  }
}

__global__ void __launch_bounds__(256)
k_step(int s, const float* feats, float* RZ, float* F, float* G4f, float* R,
       int* flags, float* GPb, float* XB, const int* Kptr, float* out, int mode) {
  __shared__ __align__(16) float LDSu[LDSF];
  do_step(s, feats, RZ, F, G4f, R, flags, GPb, XB, Kptr, out, mode, LDSu,
          blockIdx.x, threadIdx.x);
}

extern "C" void kernel_launch(void* const* d_in, const int* in_sizes, int n_in,
                              void* d_out, int out_size, void* d_ws, size_t ws_size,
                              hipStream_t stream) {
  const float* feats = (const float*)d_in[0];
  const int* Kptr = (n_in > 1) ? (const int*)d_in[1] : nullptr;
  float* ws = (float*)d_ws;
  float* RZ = ws;                        // 38400
  float* F  = ws + 38400;                // 4800
  float* G4f = ws + 43200;               // 6400 (1600 float4)
  float* R  = ws + 49600;                // 1600
  int* FLAGS = (int*)(ws + 51200);       // 16 ints (64 reserved)
  float* GPb = ws + 51264;               // 3 x 1024
  unsigned* BCNT = (unsigned*)(ws + 54336);
  unsigned* BGEN = (unsigned*)(ws + 54368);
  float* XB = ws + 54400;                // mode1: 24 x XSZ; mode0: 4 x XSZ
  const int mode = (ws_size >= (size_t)(54400 + 24 * XSZ) * 4) ? 1 : 0;

  hipMemsetAsync(ws + 54336, 0, 256, stream);  // barrier words

  float* outp = (float*)d_out;
  const float* fc = feats;
  int mv = mode;
  void* args[] = {(void*)&fc, (void*)&RZ, (void*)&F, (void*)&G4f, (void*)&R,
                  (void*)&FLAGS, (void*)&GPb, (void*)&XB, (void*)&Kptr,
                  (void*)&outp, (void*)&mv, (void*)&BCNT, (void*)&BGEN};
  hipError_t err = hipLaunchCooperativeKernel(
      (const void*)k_solve, dim3(250, 1, 1), dim3(256, 1, 1), args, 0, stream);
  if (err != hipSuccess) {
    for (int s = 0; s < NPH; ++s)
      k_step<<<dim3(250), 256, 0, stream>>>(s, fc, RZ, F, G4f, R, FLAGS, GPb,
                                            XB, Kptr, outp, mv);
  }
}